// Round 7
// baseline (155.705 us; speedup 1.0000x reference)
//
#include <hip/hip_runtime.h>
#include <hip/hip_bf16.h>
#include <math.h>

#define D_MODEL 1024
#define D_STATE 16
#define D_CONV  4
#define D_INNER 2048
#define DT_RANK 64
#define B_SZ    4
#define L_SEQ   2048

// d_out layout (floats): dt | A | B | C | x
#define OFF_DT 0
#define OFF_A  (B_SZ * D_INNER * L_SEQ)
#define OFF_B  (OFF_A + D_INNER * D_STATE)
#define OFF_C  (OFF_B + B_SZ * D_STATE * L_SEQ)
#define OFF_X  (OFF_C + B_SZ * D_STATE * L_SEQ)

typedef __attribute__((ext_vector_type(8))) short bf16x8;
typedef __attribute__((ext_vector_type(8))) unsigned short us8;
typedef __attribute__((ext_vector_type(4))) float f32x4;
typedef __attribute__((ext_vector_type(16))) float f32x16;
typedef unsigned short ushort_t;
typedef unsigned int uint_t;

static __device__ __forceinline__ ushort_t f2bf(float f) {
  __hip_bfloat16 h = __float2bfloat16(f);
  return *(ushort_t*)&h;
}
static __device__ __forceinline__ float bf2f(ushort_t u) {
  union { uint_t u; float f; } c;
  c.u = ((uint_t)u) << 16;
  return c.f;
}

// ---------------------------------------------------------------------------
// K0: fused prep — bf16 casts (hs, in_proj x-half, x_proj_w, dt_proj_w),
// zero split-K targets (xdbl, B|C), and A = -exp(A_log). One launch.
// ---------------------------------------------------------------------------
#define N4_HS   (B_SZ * L_SEQ * D_MODEL / 4)                 // 2097152
#define N4_W    (D_INNER * D_MODEL / 4)                      // 524288
#define N4_XW   ((DT_RANK + 2 * D_STATE) * D_INNER / 4)      // 49152
#define N4_DW   (D_INNER * DT_RANK / 4)                      // 32768
#define N4_Z0   (B_SZ * DT_RANK * L_SEQ / 4)                 // 131072 (xdbl)
#define N4_Z1   (2 * B_SZ * D_STATE * L_SEQ / 4)             // 65536  (B|C)
#define N4_A    (D_INNER * D_STATE / 4)                      // 8192   (A)
#define N4_TOT  (N4_HS + N4_W + N4_XW + N4_DW + N4_Z0 + N4_Z1 + N4_A)

__global__ __launch_bounds__(256) void k_prep(
    const float4* __restrict__ hs, const float4* __restrict__ ipw,
    const float4* __restrict__ xpw, const float4* __restrict__ dpw,
    const float4* __restrict__ alog,
    ushort4* __restrict__ bfHS, ushort4* __restrict__ bfW,
    ushort4* __restrict__ xwb, ushort4* __restrict__ dwb,
    float4* __restrict__ z0, float4* __restrict__ z1,
    float4* __restrict__ aout) {
  int i = blockIdx.x * 256 + threadIdx.x;
  if (i < N4_HS) {
    float4 v = hs[i];
    ushort4 o; o.x = f2bf(v.x); o.y = f2bf(v.y); o.z = f2bf(v.z); o.w = f2bf(v.w);
    bfHS[i] = o;
    return;
  }
  i -= N4_HS;
  if (i < N4_W) {
    float4 v = ipw[i];
    ushort4 o; o.x = f2bf(v.x); o.y = f2bf(v.y); o.z = f2bf(v.z); o.w = f2bf(v.w);
    bfW[i] = o;
    return;
  }
  i -= N4_W;
  if (i < N4_XW) {
    float4 v = xpw[i];
    ushort4 o; o.x = f2bf(v.x); o.y = f2bf(v.y); o.z = f2bf(v.z); o.w = f2bf(v.w);
    xwb[i] = o;
    return;
  }
  i -= N4_XW;
  if (i < N4_DW) {
    float4 v = dpw[i];
    ushort4 o; o.x = f2bf(v.x); o.y = f2bf(v.y); o.z = f2bf(v.z); o.w = f2bf(v.w);
    dwb[i] = o;
    return;
  }
  i -= N4_DW;
  if (i < N4_Z0) { z0[i] = (float4){0.f, 0.f, 0.f, 0.f}; return; }
  i -= N4_Z0;
  if (i < N4_Z1) { z1[i] = (float4){0.f, 0.f, 0.f, 0.f}; return; }
  i -= N4_Z1;
  if (i < N4_A) {
    float4 v = alog[i];
    float4 o;
    o.x = -expf(v.x); o.y = -expf(v.y); o.z = -expf(v.z); o.w = -expf(v.w);
    aout[i] = o;
  }
}

// ---------------------------------------------------------------------------
// K1: in_proj (x half) via 32x32x16 bf16 MFMA.
// C[b][d][l] = sum_k W[d][k] * HS[b][l][k]   (NT GEMM, both K-major)
// Block tile 128(M=d) x 256(N=l), BK=32; 4 waves side-by-side in N; each wave
// owns 128x64 = 4x2 tiles of 32x32 (8 f32x16 accumulators).
// Staging: global_load_lds w16, slot-swizzled source (s ^ ((row>>1)&3)).
// Output bf16.
// ---------------------------------------------------------------------------
__global__ __launch_bounds__(256) void k_inproj_mfma(
    const ushort_t* __restrict__ Wb,   // [D_INNER][D_MODEL] bf16
    const ushort_t* __restrict__ HSb,  // [B][L][D_MODEL] bf16
    ushort_t* __restrict__ Cout) {     // [B][D_INNER][L] bf16
  // grid (8, 16, 4) = 512 blocks; XCD-aware bijective swizzle (512 % 8 == 0).
  const int flat = blockIdx.x + 8 * blockIdx.y + 128 * blockIdx.z;
  const int swz  = (flat & 7) * 64 + (flat >> 3);
  const int bn = swz & 7;          // l tile (256 wide)
  const int bm = (swz >> 3) & 15;  // d tile (128 tall)
  const int b  = swz >> 7;

  __shared__ ushort_t As[128 * 32];  // [d_row][32k], slots swizzled
  __shared__ ushort_t Bs[256 * 32];  // [l_row][32k], slots swizzled
  const int tid  = threadIdx.x;
  const int wv   = tid >> 6;       // wave 0..3 -> N column of 64
  const int lane = tid & 63;
  const int l31  = lane & 31;
  const int lhi  = lane >> 5;      // 0/1

  const ushort_t* Ag = Wb + (size_t)(bm * 128) * D_MODEL;
  const ushort_t* Bg = HSb + (size_t)b * L_SEQ * D_MODEL
                           + (size_t)(bn * 256) * D_MODEL;

  f32x16 acc[4][2];
#pragma unroll
  for (int m = 0; m < 4; ++m)
#pragma unroll
    for (int n = 0; n < 2; ++n)
#pragma unroll
      for (int r = 0; r < 16; ++r) acc[m][n][r] = 0.f;

  for (int k0 = 0; k0 < D_MODEL; k0 += 32) {
    // ---- stage A: 128 rows x 32 k = 512 slots of 16B ----
#pragma unroll
    for (int q = 0; q < 2; ++q) {
      int slot = q * 256 + tid;
      int row = slot >> 2, s = slot & 3;
      int xs = s ^ ((row >> 1) & 3);
      const ushort_t* ga = Ag + (size_t)row * D_MODEL + k0 + xs * 8;
      ushort_t* la = As + (q * 256 + wv * 64) * 8;  // wave-uniform base
      __builtin_amdgcn_global_load_lds((const __attribute__((address_space(1))) void*)ga,
                                       (__attribute__((address_space(3))) void*)la, 16, 0, 0);
    }
    // ---- stage B: 256 rows x 32 k = 1024 slots ----
#pragma unroll
    for (int q = 0; q < 4; ++q) {
      int slot = q * 256 + tid;
      int row = slot >> 2, s = slot & 3;
      int xs = s ^ ((row >> 1) & 3);
      const ushort_t* gb = Bg + (size_t)row * D_MODEL + k0 + xs * 8;
      ushort_t* lb = Bs + (q * 256 + wv * 64) * 8;
      __builtin_amdgcn_global_load_lds((const __attribute__((address_space(1))) void*)gb,
                                       (__attribute__((address_space(3))) void*)lb, 16, 0, 0);
    }
    __syncthreads();

#pragma unroll
    for (int ks = 0; ks < 2; ++ks) {
      bf16x8 af[4], bfr[2];
#pragma unroll
      for (int m = 0; m < 4; ++m) {
        int row = m * 32 + l31;
        int xs = (ks * 2 + lhi) ^ ((row >> 1) & 3);
        af[m] = *(const bf16x8*)(As + (row * 4 + xs) * 8);
      }
#pragma unroll
      for (int n = 0; n < 2; ++n) {
        int row = wv * 64 + n * 32 + l31;
        int xs = (ks * 2 + lhi) ^ ((row >> 1) & 3);
        bfr[n] = *(const bf16x8*)(Bs + (row * 4 + xs) * 8);
      }
#pragma unroll
      for (int m = 0; m < 4; ++m)
#pragma unroll
        for (int n = 0; n < 2; ++n)
          acc[m][n] = __builtin_amdgcn_mfma_f32_32x32x16_bf16(af[m], bfr[n], acc[m][n], 0, 0, 0);
    }
    __syncthreads();
  }

  // ---- epilogue: C/D layout col=lane&31, row=(reg&3)+8*(reg>>2)+4*(lane>>5)
  ushort_t* Cb = Cout + (size_t)b * D_INNER * L_SEQ;
#pragma unroll
  for (int m = 0; m < 4; ++m) {
#pragma unroll
    for (int n = 0; n < 2; ++n) {
      int gc = bn * 256 + wv * 64 + n * 32 + l31;
#pragma unroll
      for (int reg = 0; reg < 16; ++reg) {
        int gr = bm * 128 + m * 32 + (reg & 3) + 8 * (reg >> 2) + 4 * lhi;
        Cb[(size_t)gr * L_SEQ + gc] = f2bf(acc[m][n][reg]);
      }
    }
  }
}

// ---------------------------------------------------------------------------
// K3: x_proj via bf16 MFMA, split-K, with conv4+SiLU fused into B-staging.
// Reads xpre (bf16 pre-conv), computes conv+SiLU in registers, writes the
// x output (fp32) as a side effect, packs bf16 B-fragments for the GEMM.
// ---------------------------------------------------------------------------
__global__ __launch_bounds__(256) void k_xproj_fused(
    const ushort_t* __restrict__ XWb,  // [96][2048] bf16
    const ushort_t* __restrict__ Xpre, // [B][D_INNER][L] bf16 (pre-conv)
    const float* __restrict__ CW,      // [D_INNER][4] conv weights
    const float* __restrict__ CB,      // [D_INNER] conv bias
    float* __restrict__ Xout,          // [B][D_INNER][L] fp32 (post conv+silu)
    float* __restrict__ XDBL,          // [B][64][L] fp32 (atomic)
    float* __restrict__ OutB,          // [B][16][L]  (atomic)
    float* __restrict__ OutC) {        // [B][16][L]  (atomic)
  const int ln = blockIdx.x;   // 0..15
  const int sk = blockIdx.y;   // 0..7
  const int b  = blockIdx.z;
  __shared__ ushort_t As[96 * 40];
  __shared__ ushort_t Bs[128 * 34];
  const int tid  = threadIdx.x;
  const int wv   = tid >> 6;
  const int lane = tid & 63;
  const int wr = wv >> 1, wc = wv & 1;
  const int ksel = lane >> 4;
  const int frow = lane & 15;

  f32x4 acc[3][4];
#pragma unroll
  for (int i = 0; i < 3; ++i)
#pragma unroll
    for (int j = 0; j < 4; ++j) acc[i][j] = (f32x4){0.f, 0.f, 0.f, 0.f};

  for (int k0 = 0; k0 < 256; k0 += 32) {
    const int koff = sk * 256 + k0;
    // ---- stage A tile [96][32] ----
    {
      int row = tid >> 2, s = tid & 3;
      bf16x8 v = *(const bf16x8*)(XWb + (size_t)row * D_INNER + koff + s * 8);
      *(bf16x8*)(As + row * 40 + s * 8) = v;
      if (tid < 128) {
        int row2 = 64 + (tid >> 2);
        bf16x8 v2 = *(const bf16x8*)(XWb + (size_t)row2 * D_INNER + koff + s * 8);
        *(bf16x8*)(As + row2 * 40 + s * 8) = v2;
      }
    }
    // ---- stage B tile: conv+silu from xpre, write x, pack bf16 ----
#pragma unroll
    for (int j = 0; j < 2; ++j) {
      int u = tid + 256 * j;
      int n4 = u & 31;           // l-quad within tile
      int kp = u >> 5;           // d-pair 0..15
      int l0 = ln * 128 + 4 * n4;
      float sv[2][4];
#pragma unroll
      for (int r = 0; r < 2; ++r) {
        int d = koff + 2 * kp + r;
        const ushort_t* row = Xpre + ((size_t)b * D_INNER + d) * L_SEQ;
        ushort4 cur = *(const ushort4*)(row + l0);
        float em3 = 0.f, em2 = 0.f, em1 = 0.f;
        if (l0 >= 4) {
          ushort4 pv = *(const ushort4*)(row + l0 - 4);
          em3 = bf2f(pv.y); em2 = bf2f(pv.z); em1 = bf2f(pv.w);
        }
        float ee[7] = {em3, em2, em1, bf2f(cur.x), bf2f(cur.y), bf2f(cur.z), bf2f(cur.w)};
        float4 w = *(const float4*)(CW + d * 4);
        float bias = CB[d];
#pragma unroll
        for (int i = 0; i < 4; ++i) {
          float v = w.x * ee[i] + w.y * ee[i + 1] + w.z * ee[i + 2] + w.w * ee[i + 3] + bias;
          sv[r][i] = v / (1.f + expf(-v));
        }
        *(float4*)(Xout + ((size_t)b * D_INNER + d) * L_SEQ + l0) =
            make_float4(sv[r][0], sv[r][1], sv[r][2], sv[r][3]);
      }
#pragma unroll
      for (int i = 0; i < 4; ++i) {
        uint_t pk = (uint_t)f2bf(sv[0][i]) | ((uint_t)f2bf(sv[1][i]) << 16);
        *(uint_t*)(Bs + (4 * n4 + i) * 34 + 2 * kp) = pk;
      }
    }
    __syncthreads();

    // ---- fragments ----
    bf16x8 af[3], bfr[4];
#pragma unroll
    for (int mi = 0; mi < 3; ++mi) {
      int row = wr * 48 + mi * 16 + frow;
      af[mi] = *(const bf16x8*)(As + row * 40 + ksel * 8);
    }
#pragma unroll
    for (int ni = 0; ni < 4; ++ni) {
      int n = wc * 64 + ni * 16 + frow;
      const uint_t* p = (const uint_t*)(Bs + n * 34);
      union { uint_t u[4]; bf16x8 v; } fr;
#pragma unroll
      for (int q = 0; q < 4; ++q) fr.u[q] = p[ksel * 4 + q];
      bfr[ni] = fr.v;
    }
#pragma unroll
    for (int mi = 0; mi < 3; ++mi)
#pragma unroll
      for (int ni = 0; ni < 4; ++ni)
        acc[mi][ni] = __builtin_amdgcn_mfma_f32_16x16x32_bf16(af[mi], bfr[ni], acc[mi][ni], 0, 0, 0);
    __syncthreads();
  }

  // ---- epilogue: atomic accumulate ----
  const int crow0 = (lane >> 4) * 4;
  const int ccol  = lane & 15;
#pragma unroll
  for (int mi = 0; mi < 3; ++mi) {
    int e0 = wr * 48 + mi * 16 + crow0;
    float* base;
    int eoff;
    if (e0 < 64)      { base = XDBL + (size_t)b * 64 * L_SEQ; eoff = e0; }
    else if (e0 < 80) { base = OutB + (size_t)b * D_STATE * L_SEQ; eoff = e0 - 64; }
    else              { base = OutC + (size_t)b * D_STATE * L_SEQ; eoff = e0 - 80; }
#pragma unroll
    for (int ni = 0; ni < 4; ++ni) {
      int l = ln * 128 + wc * 64 + ni * 16 + ccol;
#pragma unroll
      for (int r = 0; r < 4; ++r)
        atomicAdd(base + (size_t)(eoff + r) * L_SEQ + l, acc[mi][ni][r]);
    }
  }
}

// ---------------------------------------------------------------------------
// K4: dt GEMM via bf16 MFMA. DT[b][d][l] = sum_r DW[d][r] * XDBL[b][r][l].
// K=64 single-stage; 128x128 tile; 4 waves (2x2); write-bound epilogue.
// ---------------------------------------------------------------------------
__global__ __launch_bounds__(256) void k_dt_mfma(
    const ushort_t* __restrict__ DWb,  // [D_INNER][64] bf16
    const float* __restrict__ XDBL,    // [B][64][L] fp32
    float* __restrict__ DT) {          // [B][D_INNER][L] fp32
  const int ln = blockIdx.x;   // 0..15 (l tile)
  const int dm = blockIdx.y;   // 0..15 (d tile)
  const int b  = blockIdx.z;
  __shared__ ushort_t As[128 * 72];    // [d][r], pad 72
  __shared__ ushort_t Bs[128 * 68];    // [l][r], pad 68
  const int tid  = threadIdx.x;
  const int wv   = tid >> 6;
  const int lane = tid & 63;
  const int wr = wv >> 1, wc = wv & 1;
  const int ksel = lane >> 4;
  const int frow = lane & 15;

#pragma unroll
  for (int q = 0; q < 4; ++q) {
    int u = tid + 256 * q;
    int row = u >> 3, s = u & 7;
    *(bf16x8*)(As + row * 72 + s * 8) =
        *(const bf16x8*)(DWb + (size_t)(dm * 128 + row) * DT_RANK + s * 8);
  }
#pragma unroll
  for (int q = 0; q < 4; ++q) {
    int u = tid + 256 * q;
    int n4 = u & 31;
    int kp = u >> 5;
    const float* g = XDBL + ((size_t)b * DT_RANK + 2 * kp) * L_SEQ + ln * 128 + 4 * n4;
    float4 x0 = *(const float4*)g;
    float4 x1 = *(const float4*)(g + L_SEQ);
    float e0[4] = {x0.x, x0.y, x0.z, x0.w};
    float e1[4] = {x1.x, x1.y, x1.z, x1.w};
#pragma unroll
    for (int i = 0; i < 4; ++i) {
      uint_t pk = (uint_t)f2bf(e0[i]) | ((uint_t)f2bf(e1[i]) << 16);
      *(uint_t*)(Bs + (4 * n4 + i) * 68 + 2 * kp) = pk;
    }
  }
  __syncthreads();

  f32x4 acc[4][4];
#pragma unroll
  for (int i = 0; i < 4; ++i)
#pragma unroll
    for (int j = 0; j < 4; ++j) acc[i][j] = (f32x4){0.f, 0.f, 0.f, 0.f};

#pragma unroll
  for (int ks = 0; ks < 2; ++ks) {
    bf16x8 af[4], bfr[4];
#pragma unroll
    for (int m = 0; m < 4; ++m) {
      int row = wr * 64 + m * 16 + frow;
      af[m] = *(const bf16x8*)(As + row * 72 + ks * 32 + ksel * 8);
    }
#pragma unroll
    for (int n = 0; n < 4; ++n) {
      int nn = wc * 64 + n * 16 + frow;
      bfr[n] = *(const bf16x8*)(Bs + nn * 68 + ks * 32 + ksel * 8);
    }
#pragma unroll
    for (int m = 0; m < 4; ++m)
#pragma unroll
      for (int n = 0; n < 4; ++n)
        acc[m][n] = __builtin_amdgcn_mfma_f32_16x16x32_bf16(af[m], bfr[n], acc[m][n], 0, 0, 0);
  }

  const int crow0 = (lane >> 4) * 4;
  const int ccol  = lane & 15;
  float* Cb = DT + (size_t)b * D_INNER * L_SEQ;
#pragma unroll
  for (int m = 0; m < 4; ++m) {
    int gr0 = dm * 128 + wr * 64 + m * 16 + crow0;
#pragma unroll
    for (int n = 0; n < 4; ++n) {
      int gc = ln * 128 + wc * 64 + n * 16 + ccol;
#pragma unroll
      for (int i = 0; i < 4; ++i)
        Cb[(size_t)(gr0 + i) * L_SEQ + gc] = acc[m][n][i];
    }
  }
}

extern "C" void kernel_launch(void* const* d_in, const int* in_sizes, int n_in,
                              void* d_out, int out_size, void* d_ws, size_t ws_size,
                              hipStream_t stream) {
  const float* hs   = (const float*)d_in[0];
  const float* ipw  = (const float*)d_in[1];
  const float* cw   = (const float*)d_in[2];
  const float* cb   = (const float*)d_in[3];
  const float* xpw  = (const float*)d_in[4];
  const float* dpw  = (const float*)d_in[5];
  const float* alog = (const float*)d_in[6];

  float* out    = (float*)d_out;
  float* dt_out = out + OFF_DT;
  float* a_out  = out + OFF_A;
  float* b_out  = out + OFF_B;
  float* c_out  = out + OFF_C;
  float* x_out  = out + OFF_X;

  // Scratch plan:
  //  - bf16 HS (16.8 MB) + bf16 W-half (4.2 MB) in x region of d_out (dead
  //    after k_inproj; k_xproj_fused overwrites x region afterwards).
  //  - xpre (pre-conv x, bf16, 33.5 MB) in dt region (dead after xproj;
  //    k_dt_mfma overwrites).
  //  - d_ws: xdbl fp32 (2 MB) | XWb bf16 (384 KB) | DWb bf16 (256 KB).
  unsigned short* bfHS = (unsigned short*)x_out;
  unsigned short* bfW  = bfHS + (size_t)B_SZ * L_SEQ * D_MODEL;
  unsigned short* xpre = (unsigned short*)dt_out;
  float* xdbl = (float*)d_ws;
  unsigned short* xwb = (unsigned short*)((char*)d_ws + 2097152);
  unsigned short* dwb = (unsigned short*)((char*)d_ws + 2097152 + 393216);

  // One fused prep launch: 4 casts + zero xdbl + zero B|C + A = -exp(A_log).
  k_prep<<<dim3((N4_TOT + 255) / 256), 256, 0, stream>>>(
      (const float4*)hs, (const float4*)ipw, (const float4*)xpw,
      (const float4*)dpw, (const float4*)alog,
      (ushort4*)bfHS, (ushort4*)bfW, (ushort4*)xwb, (ushort4*)dwb,
      (float4*)xdbl, (float4*)b_out, (float4*)a_out);

  k_inproj_mfma<<<dim3(8, 16, 4), 256, 0, stream>>>(bfW, bfHS, xpre);
  k_xproj_fused<<<dim3(16, 8, 4), 256, 0, stream>>>(xwb, xpre, cw, cb,
                                                    x_out, xdbl, b_out, c_out);
  k_dt_mfma<<<dim3(16, 16, 4), 256, 0, stream>>>(dwb, xdbl, dt_out);
}

// Round 8
// 134.638 us; speedup vs baseline: 1.1565x; 1.1565x over previous
//
#include <hip/hip_runtime.h>
#include <hip/hip_bf16.h>
#include <math.h>

#define D_MODEL 1024
#define D_STATE 16
#define D_CONV  4
#define D_INNER 2048
#define DT_RANK 64
#define B_SZ    4
#define L_SEQ   2048

// d_out layout (floats): dt | A | B | C | x
#define OFF_DT 0
#define OFF_A  (B_SZ * D_INNER * L_SEQ)
#define OFF_B  (OFF_A + D_INNER * D_STATE)
#define OFF_C  (OFF_B + B_SZ * D_STATE * L_SEQ)
#define OFF_X  (OFF_C + B_SZ * D_STATE * L_SEQ)

typedef __attribute__((ext_vector_type(8))) short bf16x8;
typedef __attribute__((ext_vector_type(8))) unsigned short us8;
typedef __attribute__((ext_vector_type(4))) float f32x4;
typedef unsigned short ushort_t;
typedef unsigned int uint_t;

static __device__ __forceinline__ ushort_t f2bf(float f) {
  __hip_bfloat16 h = __float2bfloat16(f);
  return *(ushort_t*)&h;
}
static __device__ __forceinline__ float bf2f(ushort_t u) {
  union { uint_t u; float f; } c;
  c.u = ((uint_t)u) << 16;
  return c.f;
}

// ---------------------------------------------------------------------------
// K0: fused prep — bf16 casts (hs, in_proj x-half, x_proj_w, dt_proj_w),
// zero split-K targets (xdbl, B|C), and A = -exp(A_log). One launch.
// ---------------------------------------------------------------------------
#define N4_HS   (B_SZ * L_SEQ * D_MODEL / 4)                 // 2097152
#define N4_W    (D_INNER * D_MODEL / 4)                      // 524288
#define N4_XW   ((DT_RANK + 2 * D_STATE) * D_INNER / 4)      // 49152
#define N4_DW   (D_INNER * DT_RANK / 4)                      // 32768
#define N4_Z0   (B_SZ * DT_RANK * L_SEQ / 4)                 // 131072 (xdbl)
#define N4_Z1   (2 * B_SZ * D_STATE * L_SEQ / 4)             // 65536  (B|C)
#define N4_A    (D_INNER * D_STATE / 4)                      // 8192   (A)
#define N4_TOT  (N4_HS + N4_W + N4_XW + N4_DW + N4_Z0 + N4_Z1 + N4_A)

__global__ __launch_bounds__(256) void k_prep(
    const float4* __restrict__ hs, const float4* __restrict__ ipw,
    const float4* __restrict__ xpw, const float4* __restrict__ dpw,
    const float4* __restrict__ alog,
    ushort4* __restrict__ bfHS, ushort4* __restrict__ bfW,
    ushort4* __restrict__ xwb, ushort4* __restrict__ dwb,
    float4* __restrict__ z0, float4* __restrict__ z1,
    float4* __restrict__ aout) {
  int i = blockIdx.x * 256 + threadIdx.x;
  if (i < N4_HS) {
    float4 v = hs[i];
    ushort4 o; o.x = f2bf(v.x); o.y = f2bf(v.y); o.z = f2bf(v.z); o.w = f2bf(v.w);
    bfHS[i] = o;
    return;
  }
  i -= N4_HS;
  if (i < N4_W) {
    float4 v = ipw[i];
    ushort4 o; o.x = f2bf(v.x); o.y = f2bf(v.y); o.z = f2bf(v.z); o.w = f2bf(v.w);
    bfW[i] = o;
    return;
  }
  i -= N4_W;
  if (i < N4_XW) {
    float4 v = xpw[i];
    ushort4 o; o.x = f2bf(v.x); o.y = f2bf(v.y); o.z = f2bf(v.z); o.w = f2bf(v.w);
    xwb[i] = o;
    return;
  }
  i -= N4_XW;
  if (i < N4_DW) {
    float4 v = dpw[i];
    ushort4 o; o.x = f2bf(v.x); o.y = f2bf(v.y); o.z = f2bf(v.z); o.w = f2bf(v.w);
    dwb[i] = o;
    return;
  }
  i -= N4_DW;
  if (i < N4_Z0) { z0[i] = (float4){0.f, 0.f, 0.f, 0.f}; return; }
  i -= N4_Z0;
  if (i < N4_Z1) { z1[i] = (float4){0.f, 0.f, 0.f, 0.f}; return; }
  i -= N4_Z1;
  if (i < N4_A) {
    float4 v = alog[i];
    float4 o;
    o.x = -expf(v.x); o.y = -expf(v.y); o.z = -expf(v.z); o.w = -expf(v.w);
    aout[i] = o;
  }
}

// ---------------------------------------------------------------------------
// K1: in_proj (x half) via bf16 MFMA — round-6 structure (128x128, BK=32,
// 16x16x32, slot-XOR swizzle) + T3 minimum-2-phase LDS double buffer:
// issue next-tile global_load_lds BEFORE current-tile ds_read+MFMA; ONE
// __syncthreads per K-step (its implicit vmcnt(0) drains the prefetch).
// ---------------------------------------------------------------------------
__global__ __launch_bounds__(256) void k_inproj_mfma(
    const ushort_t* __restrict__ Wb,   // [D_INNER][D_MODEL] bf16
    const ushort_t* __restrict__ HSb,  // [B][L][D_MODEL] bf16
    ushort_t* __restrict__ Cout) {     // [B][D_INNER][L] bf16
  // XCD-aware bijective swizzle: nwg = 16*16*4 = 1024, 1024 % 8 == 0.
  const int flat = blockIdx.x + 16 * blockIdx.y + 256 * blockIdx.z;
  const int swz  = (flat & 7) * 128 + (flat >> 3);
  const int bn = swz & 15;
  const int bm = (swz >> 4) & 15;
  const int b  = swz >> 8;

  __shared__ ushort_t As[2][128 * 32];
  __shared__ ushort_t Bs[2][128 * 32];
  const int tid  = threadIdx.x;
  const int wv   = tid >> 6;
  const int lane = tid & 63;
  const int wr = wv >> 1, wc = wv & 1;

  const int srow = tid >> 2;
  const int ss   = tid & 3;

  const ushort_t* Ag = Wb + (size_t)(bm * 128) * D_MODEL;
  const ushort_t* Bg = HSb + (size_t)b * L_SEQ * D_MODEL
                           + (size_t)(bn * 128) * D_MODEL;

  f32x4 acc[4][4];
#pragma unroll
  for (int i = 0; i < 4; ++i)
#pragma unroll
    for (int j = 0; j < 4; ++j) acc[i][j] = (f32x4){0.f, 0.f, 0.f, 0.f};

  const int ksel = lane >> 4;
  const int frow = lane & 15;

  // STAGE(buf, k0): 2 issues each for A and B (128 rows x 4 slots of 16B).
#define STAGE_IN(BUF, K0)                                                        \
  do {                                                                           \
    _Pragma("unroll")                                                            \
    for (int q = 0; q < 2; ++q) {                                                \
      int row = q * 64 + srow;                                                   \
      int xs  = ss ^ ((row >> 1) & 3);                                           \
      const ushort_t* ga = Ag + (size_t)row * D_MODEL + (K0) + xs * 8;           \
      const ushort_t* gb = Bg + (size_t)row * D_MODEL + (K0) + xs * 8;           \
      ushort_t* la = As[BUF] + (q * 256 + wv * 64) * 8;                          \
      ushort_t* lb = Bs[BUF] + (q * 256 + wv * 64) * 8;                          \
      __builtin_amdgcn_global_load_lds((const __attribute__((address_space(1))) void*)ga, \
                                       (__attribute__((address_space(3))) void*)la, 16, 0, 0); \
      __builtin_amdgcn_global_load_lds((const __attribute__((address_space(1))) void*)gb, \
                                       (__attribute__((address_space(3))) void*)lb, 16, 0, 0); \
    }                                                                            \
  } while (0)

  STAGE_IN(0, 0);
  __syncthreads();  // drains vmcnt(0): buf0 ready

  const int NT = D_MODEL / 32;  // 32 K-steps
  for (int t = 0; t < NT; ++t) {
    const int cur = t & 1;
    if (t + 1 < NT) STAGE_IN(cur ^ 1, (t + 1) * 32);  // prefetch next tile

    bf16x8 af[4], bfr[4];
#pragma unroll
    for (int m = 0; m < 4; ++m) {
      int row = wr * 64 + m * 16 + frow;
      af[m] = *(const bf16x8*)(As[cur] + (row * 4 + (ksel ^ ((row >> 1) & 3))) * 8);
    }
#pragma unroll
    for (int n = 0; n < 4; ++n) {
      int row = wc * 64 + n * 16 + frow;
      bfr[n] = *(const bf16x8*)(Bs[cur] + (row * 4 + (ksel ^ ((row >> 1) & 3))) * 8);
    }
#pragma unroll
    for (int m = 0; m < 4; ++m)
#pragma unroll
      for (int n = 0; n < 4; ++n)
        acc[m][n] = __builtin_amdgcn_mfma_f32_16x16x32_bf16(af[m], bfr[n], acc[m][n], 0, 0, 0);

    __syncthreads();  // all reads of buf[cur] done AND prefetch drained
  }
#undef STAGE_IN

  const int crow0 = (lane >> 4) * 4;
  const int ccol  = lane & 15;
  ushort_t* Cb = Cout + (size_t)b * D_INNER * L_SEQ;
#pragma unroll
  for (int m = 0; m < 4; ++m) {
    int gr0 = bm * 128 + wr * 64 + m * 16 + crow0;
#pragma unroll
    for (int n = 0; n < 4; ++n) {
      int gc = bn * 128 + wc * 64 + n * 16 + ccol;
#pragma unroll
      for (int i = 0; i < 4; ++i)
        Cb[(size_t)(gr0 + i) * L_SEQ + gc] = f2bf(acc[m][n][i]);
    }
  }
}

// ---------------------------------------------------------------------------
// K3: x_proj via bf16 MFMA, split-K, with conv4+SiLU fused into B-staging.
// ---------------------------------------------------------------------------
__global__ __launch_bounds__(256) void k_xproj_fused(
    const ushort_t* __restrict__ XWb,  // [96][2048] bf16
    const ushort_t* __restrict__ Xpre, // [B][D_INNER][L] bf16 (pre-conv)
    const float* __restrict__ CW,      // [D_INNER][4] conv weights
    const float* __restrict__ CB,      // [D_INNER] conv bias
    float* __restrict__ Xout,          // [B][D_INNER][L] fp32 (post conv+silu)
    float* __restrict__ XDBL,          // [B][64][L] fp32 (atomic)
    float* __restrict__ OutB,          // [B][16][L]  (atomic)
    float* __restrict__ OutC) {        // [B][16][L]  (atomic)
  const int ln = blockIdx.x;   // 0..15
  const int sk = blockIdx.y;   // 0..7
  const int b  = blockIdx.z;
  __shared__ ushort_t As[96 * 40];
  __shared__ ushort_t Bs[128 * 34];
  const int tid  = threadIdx.x;
  const int wv   = tid >> 6;
  const int lane = tid & 63;
  const int wr = wv >> 1, wc = wv & 1;
  const int ksel = lane >> 4;
  const int frow = lane & 15;

  f32x4 acc[3][4];
#pragma unroll
  for (int i = 0; i < 3; ++i)
#pragma unroll
    for (int j = 0; j < 4; ++j) acc[i][j] = (f32x4){0.f, 0.f, 0.f, 0.f};

  for (int k0 = 0; k0 < 256; k0 += 32) {
    const int koff = sk * 256 + k0;
    // ---- stage A tile [96][32] ----
    {
      int row = tid >> 2, s = tid & 3;
      bf16x8 v = *(const bf16x8*)(XWb + (size_t)row * D_INNER + koff + s * 8);
      *(bf16x8*)(As + row * 40 + s * 8) = v;
      if (tid < 128) {
        int row2 = 64 + (tid >> 2);
        bf16x8 v2 = *(const bf16x8*)(XWb + (size_t)row2 * D_INNER + koff + s * 8);
        *(bf16x8*)(As + row2 * 40 + s * 8) = v2;
      }
    }
    // ---- stage B tile: conv+silu from xpre, write x, pack bf16 ----
#pragma unroll
    for (int j = 0; j < 2; ++j) {
      int u = tid + 256 * j;
      int n4 = u & 31;           // l-quad within tile
      int kp = u >> 5;           // d-pair 0..15
      int l0 = ln * 128 + 4 * n4;
      float sv[2][4];
#pragma unroll
      for (int r = 0; r < 2; ++r) {
        int d = koff + 2 * kp + r;
        const ushort_t* row = Xpre + ((size_t)b * D_INNER + d) * L_SEQ;
        ushort4 cur = *(const ushort4*)(row + l0);
        float em3 = 0.f, em2 = 0.f, em1 = 0.f;
        if (l0 >= 4) {
          ushort4 pv = *(const ushort4*)(row + l0 - 4);
          em3 = bf2f(pv.y); em2 = bf2f(pv.z); em1 = bf2f(pv.w);
        }
        float ee[7] = {em3, em2, em1, bf2f(cur.x), bf2f(cur.y), bf2f(cur.z), bf2f(cur.w)};
        float4 w = *(const float4*)(CW + d * 4);
        float bias = CB[d];
#pragma unroll
        for (int i = 0; i < 4; ++i) {
          float v = w.x * ee[i] + w.y * ee[i + 1] + w.z * ee[i + 2] + w.w * ee[i + 3] + bias;
          sv[r][i] = v / (1.f + expf(-v));
        }
        *(float4*)(Xout + ((size_t)b * D_INNER + d) * L_SEQ + l0) =
            make_float4(sv[r][0], sv[r][1], sv[r][2], sv[r][3]);
      }
#pragma unroll
      for (int i = 0; i < 4; ++i) {
        uint_t pk = (uint_t)f2bf(sv[0][i]) | ((uint_t)f2bf(sv[1][i]) << 16);
        *(uint_t*)(Bs + (4 * n4 + i) * 34 + 2 * kp) = pk;
      }
    }
    __syncthreads();

    // ---- fragments ----
    bf16x8 af[3], bfr[4];
#pragma unroll
    for (int mi = 0; mi < 3; ++mi) {
      int row = wr * 48 + mi * 16 + frow;
      af[mi] = *(const bf16x8*)(As + row * 40 + ksel * 8);
    }
#pragma unroll
    for (int ni = 0; ni < 4; ++ni) {
      int n = wc * 64 + ni * 16 + frow;
      const uint_t* p = (const uint_t*)(Bs + n * 34);
      union { uint_t u[4]; bf16x8 v; } fr;
#pragma unroll
      for (int q = 0; q < 4; ++q) fr.u[q] = p[ksel * 4 + q];
      bfr[ni] = fr.v;
    }
#pragma unroll
    for (int mi = 0; mi < 3; ++mi)
#pragma unroll
      for (int ni = 0; ni < 4; ++ni)
        acc[mi][ni] = __builtin_amdgcn_mfma_f32_16x16x32_bf16(af[mi], bfr[ni], acc[mi][ni], 0, 0, 0);
    __syncthreads();
  }

  // ---- epilogue: atomic accumulate ----
  const int crow0 = (lane >> 4) * 4;
  const int ccol  = lane & 15;
#pragma unroll
  for (int mi = 0; mi < 3; ++mi) {
    int e0 = wr * 48 + mi * 16 + crow0;
    float* base;
    int eoff;
    if (e0 < 64)      { base = XDBL + (size_t)b * 64 * L_SEQ; eoff = e0; }
    else if (e0 < 80) { base = OutB + (size_t)b * D_STATE * L_SEQ; eoff = e0 - 64; }
    else              { base = OutC + (size_t)b * D_STATE * L_SEQ; eoff = e0 - 80; }
#pragma unroll
    for (int ni = 0; ni < 4; ++ni) {
      int l = ln * 128 + wc * 64 + ni * 16 + ccol;
#pragma unroll
      for (int r = 0; r < 4; ++r)
        atomicAdd(base + (size_t)(eoff + r) * L_SEQ + l, acc[mi][ni][r]);
    }
  }
}

// ---------------------------------------------------------------------------
// K4: dt GEMM via bf16 MFMA. DT[b][d][l] = sum_r DW[d][r] * XDBL[b][r][l].
// K=64 single-stage; 128x128 tile; 4 waves (2x2); write-bound epilogue.
// ---------------------------------------------------------------------------
__global__ __launch_bounds__(256) void k_dt_mfma(
    const ushort_t* __restrict__ DWb,  // [D_INNER][64] bf16
    const float* __restrict__ XDBL,    // [B][64][L] fp32
    float* __restrict__ DT) {          // [B][D_INNER][L] fp32
  const int ln = blockIdx.x;   // 0..15 (l tile)
  const int dm = blockIdx.y;   // 0..15 (d tile)
  const int b  = blockIdx.z;
  __shared__ ushort_t As[128 * 72];    // [d][r], pad 72
  __shared__ ushort_t Bs[128 * 68];    // [l][r], pad 68
  const int tid  = threadIdx.x;
  const int wv   = tid >> 6;
  const int lane = tid & 63;
  const int wr = wv >> 1, wc = wv & 1;
  const int ksel = lane >> 4;
  const int frow = lane & 15;

#pragma unroll
  for (int q = 0; q < 4; ++q) {
    int u = tid + 256 * q;
    int row = u >> 3, s = u & 7;
    *(bf16x8*)(As + row * 72 + s * 8) =
        *(const bf16x8*)(DWb + (size_t)(dm * 128 + row) * DT_RANK + s * 8);
  }
#pragma unroll
  for (int q = 0; q < 4; ++q) {
    int u = tid + 256 * q;
    int n4 = u & 31;
    int kp = u >> 5;
    const float* g = XDBL + ((size_t)b * DT_RANK + 2 * kp) * L_SEQ + ln * 128 + 4 * n4;
    float4 x0 = *(const float4*)g;
    float4 x1 = *(const float4*)(g + L_SEQ);
    float e0[4] = {x0.x, x0.y, x0.z, x0.w};
    float e1[4] = {x1.x, x1.y, x1.z, x1.w};
#pragma unroll
    for (int i = 0; i < 4; ++i) {
      uint_t pk = (uint_t)f2bf(e0[i]) | ((uint_t)f2bf(e1[i]) << 16);
      *(uint_t*)(Bs + (4 * n4 + i) * 68 + 2 * kp) = pk;
    }
  }
  __syncthreads();

  f32x4 acc[4][4];
#pragma unroll
  for (int i = 0; i < 4; ++i)
#pragma unroll
    for (int j = 0; j < 4; ++j) acc[i][j] = (f32x4){0.f, 0.f, 0.f, 0.f};

#pragma unroll
  for (int ks = 0; ks < 2; ++ks) {
    bf16x8 af[4], bfr[4];
#pragma unroll
    for (int m = 0; m < 4; ++m) {
      int row = wr * 64 + m * 16 + frow;
      af[m] = *(const bf16x8*)(As + row * 72 + ks * 32 + ksel * 8);
    }
#pragma unroll
    for (int n = 0; n < 4; ++n) {
      int nn = wc * 64 + n * 16 + frow;
      bfr[n] = *(const bf16x8*)(Bs + nn * 68 + ks * 32 + ksel * 8);
    }
#pragma unroll
    for (int m = 0; m < 4; ++m)
#pragma unroll
      for (int n = 0; n < 4; ++n)
        acc[m][n] = __builtin_amdgcn_mfma_f32_16x16x32_bf16(af[m], bfr[n], acc[m][n], 0, 0, 0);
  }

  const int crow0 = (lane >> 4) * 4;
  const int ccol  = lane & 15;
  float* Cb = DT + (size_t)b * D_INNER * L_SEQ;
#pragma unroll
  for (int m = 0; m < 4; ++m) {
    int gr0 = dm * 128 + wr * 64 + m * 16 + crow0;
#pragma unroll
    for (int n = 0; n < 4; ++n) {
      int gc = ln * 128 + wc * 64 + n * 16 + ccol;
#pragma unroll
      for (int i = 0; i < 4; ++i)
        Cb[(size_t)(gr0 + i) * L_SEQ + gc] = acc[m][n][i];
    }
  }
}

extern "C" void kernel_launch(void* const* d_in, const int* in_sizes, int n_in,
                              void* d_out, int out_size, void* d_ws, size_t ws_size,
                              hipStream_t stream) {
  const float* hs   = (const float*)d_in[0];
  const float* ipw  = (const float*)d_in[1];
  const float* cw   = (const float*)d_in[2];
  const float* cb   = (const float*)d_in[3];
  const float* xpw  = (const float*)d_in[4];
  const float* dpw  = (const float*)d_in[5];
  const float* alog = (const float*)d_in[6];

  float* out    = (float*)d_out;
  float* dt_out = out + OFF_DT;
  float* a_out  = out + OFF_A;
  float* b_out  = out + OFF_B;
  float* c_out  = out + OFF_C;
  float* x_out  = out + OFF_X;

  // Scratch plan:
  //  - bf16 HS (16.8 MB) + bf16 W-half (4.2 MB) in x region of d_out (dead
  //    after k_inproj; k_xproj_fused overwrites x region afterwards).
  //  - xpre (pre-conv x, bf16, 33.5 MB) in dt region (dead after xproj;
  //    k_dt_mfma overwrites).
  //  - d_ws: xdbl fp32 (2 MB) | XWb bf16 (384 KB) | DWb bf16 (256 KB).
  unsigned short* bfHS = (unsigned short*)x_out;
  unsigned short* bfW  = bfHS + (size_t)B_SZ * L_SEQ * D_MODEL;
  unsigned short* xpre = (unsigned short*)dt_out;
  float* xdbl = (float*)d_ws;
  unsigned short* xwb = (unsigned short*)((char*)d_ws + 2097152);
  unsigned short* dwb = (unsigned short*)((char*)d_ws + 2097152 + 393216);

  // One fused prep launch: 4 casts + zero xdbl + zero B|C + A = -exp(A_log).
  k_prep<<<dim3((N4_TOT + 255) / 256), 256, 0, stream>>>(
      (const float4*)hs, (const float4*)ipw, (const float4*)xpw,
      (const float4*)dpw, (const float4*)alog,
      (ushort4*)bfHS, (ushort4*)bfW, (ushort4*)xwb, (ushort4*)dwb,
      (float4*)xdbl, (float4*)b_out, (float4*)a_out);

  k_inproj_mfma<<<dim3(16, 16, 4), 256, 0, stream>>>(bfW, bfHS, xpre);
  k_xproj_fused<<<dim3(16, 8, 4), 256, 0, stream>>>(xwb, xpre, cw, cb,
                                                    x_out, xdbl, b_out, c_out);
  k_dt_mfma<<<dim3(16, 16, 4), 256, 0, stream>>>(dwb, xdbl, dt_out);
}

// Round 9
// 129.745 us; speedup vs baseline: 1.2001x; 1.0377x over previous
//
#include <hip/hip_runtime.h>
#include <hip/hip_bf16.h>
#include <math.h>

#define D_MODEL 1024
#define D_STATE 16
#define D_CONV  4
#define D_INNER 2048
#define DT_RANK 64
#define B_SZ    4
#define L_SEQ   2048

// d_out layout (floats): dt | A | B | C | x
#define OFF_DT 0
#define OFF_A  (B_SZ * D_INNER * L_SEQ)
#define OFF_B  (OFF_A + D_INNER * D_STATE)
#define OFF_C  (OFF_B + B_SZ * D_STATE * L_SEQ)
#define OFF_X  (OFF_C + B_SZ * D_STATE * L_SEQ)

typedef __attribute__((ext_vector_type(8))) short bf16x8;
typedef __attribute__((ext_vector_type(8))) unsigned short us8;
typedef __attribute__((ext_vector_type(4))) float f32x4;
typedef unsigned short ushort_t;
typedef unsigned int uint_t;

static __device__ __forceinline__ ushort_t f2bf(float f) {
  __hip_bfloat16 h = __float2bfloat16(f);
  return *(ushort_t*)&h;
}
static __device__ __forceinline__ float bf2f(ushort_t u) {
  union { uint_t u; float f; } c;
  c.u = ((uint_t)u) << 16;
  return c.f;
}

// ---------------------------------------------------------------------------
// K0: fused prep — bf16 casts (hs, in_proj x-half, x_proj_w, dt_proj_w),
// zero split-K targets (xdbl, B|C), and A = -exp(A_log). One launch.
// ---------------------------------------------------------------------------
#define N4_HS   (B_SZ * L_SEQ * D_MODEL / 4)                 // 2097152
#define N4_W    (D_INNER * D_MODEL / 4)                      // 524288
#define N4_XW   ((DT_RANK + 2 * D_STATE) * D_INNER / 4)      // 49152
#define N4_DW   (D_INNER * DT_RANK / 4)                      // 32768
#define N4_Z0   (B_SZ * DT_RANK * L_SEQ / 4)                 // 131072 (xdbl)
#define N4_Z1   (2 * B_SZ * D_STATE * L_SEQ / 4)             // 65536  (B|C)
#define N4_A    (D_INNER * D_STATE / 4)                      // 8192   (A)
#define N4_TOT  (N4_HS + N4_W + N4_XW + N4_DW + N4_Z0 + N4_Z1 + N4_A)

__global__ __launch_bounds__(256) void k_prep(
    const float4* __restrict__ hs, const float4* __restrict__ ipw,
    const float4* __restrict__ xpw, const float4* __restrict__ dpw,
    const float4* __restrict__ alog,
    ushort4* __restrict__ bfHS, ushort4* __restrict__ bfW,
    ushort4* __restrict__ xwb, ushort4* __restrict__ dwb,
    float4* __restrict__ z0, float4* __restrict__ z1,
    float4* __restrict__ aout) {
  int i = blockIdx.x * 256 + threadIdx.x;
  if (i < N4_HS) {
    float4 v = hs[i];
    ushort4 o; o.x = f2bf(v.x); o.y = f2bf(v.y); o.z = f2bf(v.z); o.w = f2bf(v.w);
    bfHS[i] = o;
    return;
  }
  i -= N4_HS;
  if (i < N4_W) {
    float4 v = ipw[i];
    ushort4 o; o.x = f2bf(v.x); o.y = f2bf(v.y); o.z = f2bf(v.z); o.w = f2bf(v.w);
    bfW[i] = o;
    return;
  }
  i -= N4_W;
  if (i < N4_XW) {
    float4 v = xpw[i];
    ushort4 o; o.x = f2bf(v.x); o.y = f2bf(v.y); o.z = f2bf(v.z); o.w = f2bf(v.w);
    xwb[i] = o;
    return;
  }
  i -= N4_XW;
  if (i < N4_DW) {
    float4 v = dpw[i];
    ushort4 o; o.x = f2bf(v.x); o.y = f2bf(v.y); o.z = f2bf(v.z); o.w = f2bf(v.w);
    dwb[i] = o;
    return;
  }
  i -= N4_DW;
  if (i < N4_Z0) { z0[i] = (float4){0.f, 0.f, 0.f, 0.f}; return; }
  i -= N4_Z0;
  if (i < N4_Z1) { z1[i] = (float4){0.f, 0.f, 0.f, 0.f}; return; }
  i -= N4_Z1;
  if (i < N4_A) {
    float4 v = alog[i];
    float4 o;
    o.x = -expf(v.x); o.y = -expf(v.y); o.z = -expf(v.z); o.w = -expf(v.w);
    aout[i] = o;
  }
}

// ---------------------------------------------------------------------------
// K1: in_proj (x half) via bf16 MFMA. 128x128 tile, BK=32, 16x16x32.
// This round: (a) counted-vmcnt 2-deep pipeline: raw s_barrier + vmcnt(4)
// so prefetched loads stay in flight across barriers (T4); (b) LDS-staged
// coalesced bf16 epilogue (256B stores instead of 64 scattered 2B stores).
// Pipeline ledger (4 gl_lds per STAGE per thread):
//   prologue: STAGE(t0), STAGE(t1) -> 8 out; vmcnt(4) => t0 landed; barrier.
//   iter t:   compute(t); sched_barrier; barrier(B1: all reads done);
//             STAGE(t+2) -> 8 out; vmcnt(4) => t+1 landed; barrier(B2).
//   tail:     compute(30); barrier; vmcnt(0) => t31 landed; barrier;
//             compute(31); syncthreads; LDS epilogue.
// ---------------------------------------------------------------------------
__global__ __launch_bounds__(256) void k_inproj_mfma(
    const ushort_t* __restrict__ Wb,   // [D_INNER][D_MODEL] bf16
    const ushort_t* __restrict__ HSb,  // [B][L][D_MODEL] bf16
    ushort_t* __restrict__ Cout) {     // [B][D_INNER][L] bf16
  // XCD-aware bijective swizzle: nwg = 16*16*4 = 1024, 1024 % 8 == 0.
  const int flat = blockIdx.x + 16 * blockIdx.y + 256 * blockIdx.z;
  const int swz  = (flat & 7) * 128 + (flat >> 3);
  const int bn = swz & 15;
  const int bm = (swz >> 4) & 15;
  const int b  = swz >> 8;

  // sh layout: buf0 A [0,4096) | buf0 B [4096,8192) | buf1 A [8192,12288)
  //            buf1 B [12288,16384) ; epilogue reuses sh as [128][136].
  __shared__ ushort_t sh[128 * 136];
  const int tid  = threadIdx.x;
  const int wv   = tid >> 6;
  const int lane = tid & 63;
  const int wr = wv >> 1, wc = wv & 1;

  const int srow = tid >> 2;
  const int ss   = tid & 3;

  const ushort_t* Ag = Wb + (size_t)(bm * 128) * D_MODEL;
  const ushort_t* Bg = HSb + (size_t)b * L_SEQ * D_MODEL
                           + (size_t)(bn * 128) * D_MODEL;

  f32x4 acc[4][4];
#pragma unroll
  for (int i = 0; i < 4; ++i)
#pragma unroll
    for (int j = 0; j < 4; ++j) acc[i][j] = (f32x4){0.f, 0.f, 0.f, 0.f};

  const int ksel = lane >> 4;
  const int frow = lane & 15;

  // 4 global_load_lds per thread per STAGE (2 A + 2 B), 16B each.
#define STAGE_IN(BUF, K0)                                                        \
  do {                                                                           \
    _Pragma("unroll")                                                            \
    for (int q = 0; q < 2; ++q) {                                                \
      int row = q * 64 + srow;                                                   \
      int xs  = ss ^ ((row >> 1) & 3);                                           \
      const ushort_t* ga = Ag + (size_t)row * D_MODEL + (K0) + xs * 8;           \
      const ushort_t* gb = Bg + (size_t)row * D_MODEL + (K0) + xs * 8;           \
      ushort_t* la = sh + (BUF) * 8192 + (q * 256 + wv * 64) * 8;                \
      ushort_t* lb = sh + (BUF) * 8192 + 4096 + (q * 256 + wv * 64) * 8;         \
      __builtin_amdgcn_global_load_lds((const __attribute__((address_space(1))) void*)ga, \
                                       (__attribute__((address_space(3))) void*)la, 16, 0, 0); \
      __builtin_amdgcn_global_load_lds((const __attribute__((address_space(1))) void*)gb, \
                                       (__attribute__((address_space(3))) void*)lb, 16, 0, 0); \
    }                                                                            \
  } while (0)

#define COMPUTE(BUF)                                                             \
  do {                                                                           \
    const ushort_t* Ab = sh + (BUF) * 8192;                                      \
    const ushort_t* Bb = sh + (BUF) * 8192 + 4096;                               \
    bf16x8 af[4], bfr[4];                                                        \
    _Pragma("unroll")                                                            \
    for (int m = 0; m < 4; ++m) {                                                \
      int row = wr * 64 + m * 16 + frow;                                         \
      af[m] = *(const bf16x8*)(Ab + (row * 4 + (ksel ^ ((row >> 1) & 3))) * 8);  \
    }                                                                            \
    _Pragma("unroll")                                                            \
    for (int n = 0; n < 4; ++n) {                                                \
      int row = wc * 64 + n * 16 + frow;                                         \
      bfr[n] = *(const bf16x8*)(Bb + (row * 4 + (ksel ^ ((row >> 1) & 3))) * 8); \
    }                                                                            \
    _Pragma("unroll")                                                            \
    for (int m = 0; m < 4; ++m)                                                  \
      _Pragma("unroll")                                                          \
      for (int n = 0; n < 4; ++n)                                                \
        acc[m][n] = __builtin_amdgcn_mfma_f32_16x16x32_bf16(af[m], bfr[n], acc[m][n], 0, 0, 0); \
  } while (0)

  // ---- prologue: stage tiles 0 and 1 ----
  STAGE_IN(0, 0);
  STAGE_IN(1, 32);
  asm volatile("s_waitcnt vmcnt(4)" ::: "memory");  // tile 0 landed
  __builtin_amdgcn_s_barrier();

  // ---- main loop: tiles 0..29, staging tiles 2..31 ----
  for (int t = 0; t < 30; ++t) {
    COMPUTE(t & 1);
    __builtin_amdgcn_sched_barrier(0);
    __builtin_amdgcn_s_barrier();                    // B1: buf[t&1] free
    STAGE_IN(t & 1, (t + 2) * 32);
    asm volatile("s_waitcnt vmcnt(4)" ::: "memory"); // tile t+1 landed
    __builtin_amdgcn_s_barrier();                    // B2: next tile ready
    __builtin_amdgcn_sched_barrier(0);
  }
  // ---- tail: tiles 30, 31 ----
  COMPUTE(0);
  __builtin_amdgcn_sched_barrier(0);
  __builtin_amdgcn_s_barrier();
  asm volatile("s_waitcnt vmcnt(0)" ::: "memory");   // tile 31 landed
  __builtin_amdgcn_s_barrier();
  COMPUTE(1);
#undef STAGE_IN
#undef COMPUTE

  __syncthreads();  // all LDS buffer reads done; reuse sh for epilogue

  // ---- epilogue: stage bf16 C-tile in LDS [128][136], then 256B stores ----
  const int crow0 = (lane >> 4) * 4;
  const int ccol  = lane & 15;
#pragma unroll
  for (int m = 0; m < 4; ++m) {
#pragma unroll
    for (int n = 0; n < 4; ++n) {
      int r0 = wr * 64 + m * 16 + crow0;
      int c  = wc * 64 + n * 16 + ccol;
#pragma unroll
      for (int i = 0; i < 4; ++i)
        sh[(r0 + i) * 136 + c] = f2bf(acc[m][n][i]);
    }
  }
  __syncthreads();
  ushort_t* Cb = Cout + (size_t)b * D_INNER * L_SEQ
                      + (size_t)(bm * 128) * L_SEQ + bn * 128;
#pragma unroll
  for (int q = 0; q < 8; ++q) {
    int idx = q * 256 + tid;      // 2048 16B-chunks
    int r   = idx >> 4;
    int c16 = idx & 15;
    us8 v = *(const us8*)(sh + r * 136 + c16 * 8);
    *(us8*)(Cb + (size_t)r * L_SEQ + c16 * 8) = v;
  }
}

// ---------------------------------------------------------------------------
// K3: x_proj via bf16 MFMA, split-K, with conv4+SiLU fused into B-staging.
// ---------------------------------------------------------------------------
__global__ __launch_bounds__(256) void k_xproj_fused(
    const ushort_t* __restrict__ XWb,  // [96][2048] bf16
    const ushort_t* __restrict__ Xpre, // [B][D_INNER][L] bf16 (pre-conv)
    const float* __restrict__ CW,      // [D_INNER][4] conv weights
    const float* __restrict__ CB,      // [D_INNER] conv bias
    float* __restrict__ Xout,          // [B][D_INNER][L] fp32 (post conv+silu)
    float* __restrict__ XDBL,          // [B][64][L] fp32 (atomic)
    float* __restrict__ OutB,          // [B][16][L]  (atomic)
    float* __restrict__ OutC) {        // [B][16][L]  (atomic)
  const int ln = blockIdx.x;   // 0..15
  const int sk = blockIdx.y;   // 0..7
  const int b  = blockIdx.z;
  __shared__ ushort_t As[96 * 40];
  __shared__ ushort_t Bs[128 * 34];
  const int tid  = threadIdx.x;
  const int wv   = tid >> 6;
  const int lane = tid & 63;
  const int wr = wv >> 1, wc = wv & 1;
  const int ksel = lane >> 4;
  const int frow = lane & 15;

  f32x4 acc[3][4];
#pragma unroll
  for (int i = 0; i < 3; ++i)
#pragma unroll
    for (int j = 0; j < 4; ++j) acc[i][j] = (f32x4){0.f, 0.f, 0.f, 0.f};

  for (int k0 = 0; k0 < 256; k0 += 32) {
    const int koff = sk * 256 + k0;
    // ---- stage A tile [96][32] ----
    {
      int row = tid >> 2, s = tid & 3;
      bf16x8 v = *(const bf16x8*)(XWb + (size_t)row * D_INNER + koff + s * 8);
      *(bf16x8*)(As + row * 40 + s * 8) = v;
      if (tid < 128) {
        int row2 = 64 + (tid >> 2);
        bf16x8 v2 = *(const bf16x8*)(XWb + (size_t)row2 * D_INNER + koff + s * 8);
        *(bf16x8*)(As + row2 * 40 + s * 8) = v2;
      }
    }
    // ---- stage B tile: conv+silu from xpre, write x, pack bf16 ----
#pragma unroll
    for (int j = 0; j < 2; ++j) {
      int u = tid + 256 * j;
      int n4 = u & 31;           // l-quad within tile
      int kp = u >> 5;           // d-pair 0..15
      int l0 = ln * 128 + 4 * n4;
      float sv[2][4];
#pragma unroll
      for (int r = 0; r < 2; ++r) {
        int d = koff + 2 * kp + r;
        const ushort_t* row = Xpre + ((size_t)b * D_INNER + d) * L_SEQ;
        ushort4 cur = *(const ushort4*)(row + l0);
        float em3 = 0.f, em2 = 0.f, em1 = 0.f;
        if (l0 >= 4) {
          ushort4 pv = *(const ushort4*)(row + l0 - 4);
          em3 = bf2f(pv.y); em2 = bf2f(pv.z); em1 = bf2f(pv.w);
        }
        float ee[7] = {em3, em2, em1, bf2f(cur.x), bf2f(cur.y), bf2f(cur.z), bf2f(cur.w)};
        float4 w = *(const float4*)(CW + d * 4);
        float bias = CB[d];
#pragma unroll
        for (int i = 0; i < 4; ++i) {
          float v = w.x * ee[i] + w.y * ee[i + 1] + w.z * ee[i + 2] + w.w * ee[i + 3] + bias;
          sv[r][i] = v / (1.f + expf(-v));
        }
        *(float4*)(Xout + ((size_t)b * D_INNER + d) * L_SEQ + l0) =
            make_float4(sv[r][0], sv[r][1], sv[r][2], sv[r][3]);
      }
#pragma unroll
      for (int i = 0; i < 4; ++i) {
        uint_t pk = (uint_t)f2bf(sv[0][i]) | ((uint_t)f2bf(sv[1][i]) << 16);
        *(uint_t*)(Bs + (4 * n4 + i) * 34 + 2 * kp) = pk;
      }
    }
    __syncthreads();

    // ---- fragments ----
    bf16x8 af[3], bfr[4];
#pragma unroll
    for (int mi = 0; mi < 3; ++mi) {
      int row = wr * 48 + mi * 16 + frow;
      af[mi] = *(const bf16x8*)(As + row * 40 + ksel * 8);
    }
#pragma unroll
    for (int ni = 0; ni < 4; ++ni) {
      int n = wc * 64 + ni * 16 + frow;
      const uint_t* p = (const uint_t*)(Bs + n * 34);
      union { uint_t u[4]; bf16x8 v; } fr;
#pragma unroll
      for (int q = 0; q < 4; ++q) fr.u[q] = p[ksel * 4 + q];
      bfr[ni] = fr.v;
    }
#pragma unroll
    for (int mi = 0; mi < 3; ++mi)
#pragma unroll
      for (int ni = 0; ni < 4; ++ni)
        acc[mi][ni] = __builtin_amdgcn_mfma_f32_16x16x32_bf16(af[mi], bfr[ni], acc[mi][ni], 0, 0, 0);
    __syncthreads();
  }

  // ---- epilogue: atomic accumulate ----
  const int crow0 = (lane >> 4) * 4;
  const int ccol  = lane & 15;
#pragma unroll
  for (int mi = 0; mi < 3; ++mi) {
    int e0 = wr * 48 + mi * 16 + crow0;
    float* base;
    int eoff;
    if (e0 < 64)      { base = XDBL + (size_t)b * 64 * L_SEQ; eoff = e0; }
    else if (e0 < 80) { base = OutB + (size_t)b * D_STATE * L_SEQ; eoff = e0 - 64; }
    else              { base = OutC + (size_t)b * D_STATE * L_SEQ; eoff = e0 - 80; }
#pragma unroll
    for (int ni = 0; ni < 4; ++ni) {
      int l = ln * 128 + wc * 64 + ni * 16 + ccol;
#pragma unroll
      for (int r = 0; r < 4; ++r)
        atomicAdd(base + (size_t)(eoff + r) * L_SEQ + l, acc[mi][ni][r]);
    }
  }
}

// ---------------------------------------------------------------------------
// K4: dt GEMM via bf16 MFMA. DT[b][d][l] = sum_r DW[d][r] * XDBL[b][r][l].
// K=64 single-stage; 128x128 tile; 4 waves (2x2); write-bound epilogue.
// ---------------------------------------------------------------------------
__global__ __launch_bounds__(256) void k_dt_mfma(
    const ushort_t* __restrict__ DWb,  // [D_INNER][64] bf16
    const float* __restrict__ XDBL,    // [B][64][L] fp32
    float* __restrict__ DT) {          // [B][D_INNER][L] fp32
  const int ln = blockIdx.x;   // 0..15 (l tile)
  const int dm = blockIdx.y;   // 0..15 (d tile)
  const int b  = blockIdx.z;
  __shared__ ushort_t As[128 * 72];    // [d][r], pad 72
  __shared__ ushort_t Bs[128 * 68];    // [l][r], pad 68
  const int tid  = threadIdx.x;
  const int wv   = tid >> 6;
  const int lane = tid & 63;
  const int wr = wv >> 1, wc = wv & 1;
  const int ksel = lane >> 4;
  const int frow = lane & 15;

#pragma unroll
  for (int q = 0; q < 4; ++q) {
    int u = tid + 256 * q;
    int row = u >> 3, s = u & 7;
    *(bf16x8*)(As + row * 72 + s * 8) =
        *(const bf16x8*)(DWb + (size_t)(dm * 128 + row) * DT_RANK + s * 8);
  }
#pragma unroll
  for (int q = 0; q < 4; ++q) {
    int u = tid + 256 * q;
    int n4 = u & 31;
    int kp = u >> 5;
    const float* g = XDBL + ((size_t)b * DT_RANK + 2 * kp) * L_SEQ + ln * 128 + 4 * n4;
    float4 x0 = *(const float4*)g;
    float4 x1 = *(const float4*)(g + L_SEQ);
    float e0[4] = {x0.x, x0.y, x0.z, x0.w};
    float e1[4] = {x1.x, x1.y, x1.z, x1.w};
#pragma unroll
    for (int i = 0; i < 4; ++i) {
      uint_t pk = (uint_t)f2bf(e0[i]) | ((uint_t)f2bf(e1[i]) << 16);
      *(uint_t*)(Bs + (4 * n4 + i) * 68 + 2 * kp) = pk;
    }
  }
  __syncthreads();

  f32x4 acc[4][4];
#pragma unroll
  for (int i = 0; i < 4; ++i)
#pragma unroll
    for (int j = 0; j < 4; ++j) acc[i][j] = (f32x4){0.f, 0.f, 0.f, 0.f};

#pragma unroll
  for (int ks = 0; ks < 2; ++ks) {
    bf16x8 af[4], bfr[4];
#pragma unroll
    for (int m = 0; m < 4; ++m) {
      int row = wr * 64 + m * 16 + frow;
      af[m] = *(const bf16x8*)(As + row * 72 + ks * 32 + ksel * 8);
    }
#pragma unroll
    for (int n = 0; n < 4; ++n) {
      int nn = wc * 64 + n * 16 + frow;
      bfr[n] = *(const bf16x8*)(Bs + nn * 68 + ks * 32 + ksel * 8);
    }
#pragma unroll
    for (int m = 0; m < 4; ++m)
#pragma unroll
      for (int n = 0; n < 4; ++n)
        acc[m][n] = __builtin_amdgcn_mfma_f32_16x16x32_bf16(af[m], bfr[n], acc[m][n], 0, 0, 0);
  }

  const int crow0 = (lane >> 4) * 4;
  const int ccol  = lane & 15;
  float* Cb = DT + (size_t)b * D_INNER * L_SEQ;
#pragma unroll
  for (int m = 0; m < 4; ++m) {
    int gr0 = dm * 128 + wr * 64 + m * 16 + crow0;
#pragma unroll
    for (int n = 0; n < 4; ++n) {
      int gc = ln * 128 + wc * 64 + n * 16 + ccol;
#pragma unroll
      for (int i = 0; i < 4; ++i)
        Cb[(size_t)(gr0 + i) * L_SEQ + gc] = acc[m][n][i];
    }
  }
}

extern "C" void kernel_launch(void* const* d_in, const int* in_sizes, int n_in,
                              void* d_out, int out_size, void* d_ws, size_t ws_size,
                              hipStream_t stream) {
  const float* hs   = (const float*)d_in[0];
  const float* ipw  = (const float*)d_in[1];
  const float* cw   = (const float*)d_in[2];
  const float* cb   = (const float*)d_in[3];
  const float* xpw  = (const float*)d_in[4];
  const float* dpw  = (const float*)d_in[5];
  const float* alog = (const float*)d_in[6];

  float* out    = (float*)d_out;
  float* dt_out = out + OFF_DT;
  float* a_out  = out + OFF_A;
  float* b_out  = out + OFF_B;
  float* c_out  = out + OFF_C;
  float* x_out  = out + OFF_X;

  // Scratch plan:
  //  - bf16 HS (16.8 MB) + bf16 W-half (4.2 MB) in x region of d_out (dead
  //    after k_inproj; k_xproj_fused overwrites x region afterwards).
  //  - xpre (pre-conv x, bf16, 33.5 MB) in dt region (dead after xproj;
  //    k_dt_mfma overwrites).
  //  - d_ws: xdbl fp32 (2 MB) | XWb bf16 (384 KB) | DWb bf16 (256 KB).
  unsigned short* bfHS = (unsigned short*)x_out;
  unsigned short* bfW  = bfHS + (size_t)B_SZ * L_SEQ * D_MODEL;
  unsigned short* xpre = (unsigned short*)dt_out;
  float* xdbl = (float*)d_ws;
  unsigned short* xwb = (unsigned short*)((char*)d_ws + 2097152);
  unsigned short* dwb = (unsigned short*)((char*)d_ws + 2097152 + 393216);

  // One fused prep launch: 4 casts + zero xdbl + zero B|C + A = -exp(A_log).
  k_prep<<<dim3((N4_TOT + 255) / 256), 256, 0, stream>>>(
      (const float4*)hs, (const float4*)ipw, (const float4*)xpw,
      (const float4*)dpw, (const float4*)alog,
      (ushort4*)bfHS, (ushort4*)bfW, (ushort4*)xwb, (ushort4*)dwb,
      (float4*)xdbl, (float4*)b_out, (float4*)a_out);

  k_inproj_mfma<<<dim3(16, 16, 4), 256, 0, stream>>>(bfW, bfHS, xpre);
  k_xproj_fused<<<dim3(16, 8, 4), 256, 0, stream>>>(xwb, xpre, cw, cb,
                                                    x_out, xdbl, b_out, c_out);
  k_dt_mfma<<<dim3(16, 16, 4), 256, 0, stream>>>(dwb, xdbl, dt_out);
}

// Round 11
// 125.277 us; speedup vs baseline: 1.2429x; 1.0357x over previous
//
#include <hip/hip_runtime.h>
#include <hip/hip_bf16.h>
#include <math.h>

#define D_MODEL 1024
#define D_STATE 16
#define D_CONV  4
#define D_INNER 2048
#define DT_RANK 64
#define B_SZ    4
#define L_SEQ   2048

// d_out layout (floats): dt | A | B | C | x
#define OFF_DT 0
#define OFF_A  (B_SZ * D_INNER * L_SEQ)
#define OFF_B  (OFF_A + D_INNER * D_STATE)
#define OFF_C  (OFF_B + B_SZ * D_STATE * L_SEQ)
#define OFF_X  (OFF_C + B_SZ * D_STATE * L_SEQ)

typedef __attribute__((ext_vector_type(8))) short bf16x8;
typedef __attribute__((ext_vector_type(8))) unsigned short us8;
typedef __attribute__((ext_vector_type(4))) float f32x4;
typedef unsigned short ushort_t;
typedef unsigned int uint_t;

static __device__ __forceinline__ ushort_t f2bf(float f) {
  __hip_bfloat16 h = __float2bfloat16(f);
  return *(ushort_t*)&h;
}
static __device__ __forceinline__ float bf2f(ushort_t u) {
  union { uint_t u; float f; } c;
  c.u = ((uint_t)u) << 16;
  return c.f;
}

// ---------------------------------------------------------------------------
// K0: fused prep — bf16 casts (hs, in_proj x-half, x_proj_w, dt_proj_w),
// zero split-K targets (xdbl, B|C), and A = -exp(A_log). One launch.
// ---------------------------------------------------------------------------
#define N4_HS   (B_SZ * L_SEQ * D_MODEL / 4)                 // 2097152
#define N4_W    (D_INNER * D_MODEL / 4)                      // 524288
#define N4_XW   ((DT_RANK + 2 * D_STATE) * D_INNER / 4)      // 49152
#define N4_DW   (D_INNER * DT_RANK / 4)                      // 32768
#define N4_Z0   (B_SZ * DT_RANK * L_SEQ / 4)                 // 131072 (xdbl)
#define N4_Z1   (2 * B_SZ * D_STATE * L_SEQ / 4)             // 65536  (B|C)
#define N4_A    (D_INNER * D_STATE / 4)                      // 8192   (A)
#define N4_TOT  (N4_HS + N4_W + N4_XW + N4_DW + N4_Z0 + N4_Z1 + N4_A)

__global__ __launch_bounds__(256) void k_prep(
    const float4* __restrict__ hs, const float4* __restrict__ ipw,
    const float4* __restrict__ xpw, const float4* __restrict__ dpw,
    const float4* __restrict__ alog,
    ushort4* __restrict__ bfHS, ushort4* __restrict__ bfW,
    ushort4* __restrict__ xwb, ushort4* __restrict__ dwb,
    float4* __restrict__ z0, float4* __restrict__ z1,
    float4* __restrict__ aout) {
  int i = blockIdx.x * 256 + threadIdx.x;
  if (i < N4_HS) {
    float4 v = hs[i];
    ushort4 o; o.x = f2bf(v.x); o.y = f2bf(v.y); o.z = f2bf(v.z); o.w = f2bf(v.w);
    bfHS[i] = o;
    return;
  }
  i -= N4_HS;
  if (i < N4_W) {
    float4 v = ipw[i];
    ushort4 o; o.x = f2bf(v.x); o.y = f2bf(v.y); o.z = f2bf(v.z); o.w = f2bf(v.w);
    bfW[i] = o;
    return;
  }
  i -= N4_W;
  if (i < N4_XW) {
    float4 v = xpw[i];
    ushort4 o; o.x = f2bf(v.x); o.y = f2bf(v.y); o.z = f2bf(v.z); o.w = f2bf(v.w);
    xwb[i] = o;
    return;
  }
  i -= N4_XW;
  if (i < N4_DW) {
    float4 v = dpw[i];
    ushort4 o; o.x = f2bf(v.x); o.y = f2bf(v.y); o.z = f2bf(v.z); o.w = f2bf(v.w);
    dwb[i] = o;
    return;
  }
  i -= N4_DW;
  if (i < N4_Z0) { z0[i] = (float4){0.f, 0.f, 0.f, 0.f}; return; }
  i -= N4_Z0;
  if (i < N4_Z1) { z1[i] = (float4){0.f, 0.f, 0.f, 0.f}; return; }
  i -= N4_Z1;
  if (i < N4_A) {
    float4 v = alog[i];
    float4 o;
    o.x = -expf(v.x); o.y = -expf(v.y); o.z = -expf(v.z); o.w = -expf(v.w);
    aout[i] = o;
  }
}

// ---------------------------------------------------------------------------
// K1: in_proj (x half) via bf16 MFMA. 128x128 tile, BK=32, 16x16x32.
// Counted-vmcnt 2-deep pipeline (T4) + LDS-staged coalesced bf16 epilogue.
// (unchanged from round 9)
// ---------------------------------------------------------------------------
__global__ __launch_bounds__(256) void k_inproj_mfma(
    const ushort_t* __restrict__ Wb,   // [D_INNER][D_MODEL] bf16
    const ushort_t* __restrict__ HSb,  // [B][L][D_MODEL] bf16
    ushort_t* __restrict__ Cout) {     // [B][D_INNER][L] bf16
  const int flat = blockIdx.x + 16 * blockIdx.y + 256 * blockIdx.z;
  const int swz  = (flat & 7) * 128 + (flat >> 3);
  const int bn = swz & 15;
  const int bm = (swz >> 4) & 15;
  const int b  = swz >> 8;

  __shared__ ushort_t sh[128 * 136];
  const int tid  = threadIdx.x;
  const int wv   = tid >> 6;
  const int lane = tid & 63;
  const int wr = wv >> 1, wc = wv & 1;

  const int srow = tid >> 2;
  const int ss   = tid & 3;

  const ushort_t* Ag = Wb + (size_t)(bm * 128) * D_MODEL;
  const ushort_t* Bg = HSb + (size_t)b * L_SEQ * D_MODEL
                           + (size_t)(bn * 128) * D_MODEL;

  f32x4 acc[4][4];
#pragma unroll
  for (int i = 0; i < 4; ++i)
#pragma unroll
    for (int j = 0; j < 4; ++j) acc[i][j] = (f32x4){0.f, 0.f, 0.f, 0.f};

  const int ksel = lane >> 4;
  const int frow = lane & 15;

#define STAGE_IN(BUF, K0)                                                        \
  do {                                                                           \
    _Pragma("unroll")                                                            \
    for (int q = 0; q < 2; ++q) {                                                \
      int row = q * 64 + srow;                                                   \
      int xs  = ss ^ ((row >> 1) & 3);                                           \
      const ushort_t* ga = Ag + (size_t)row * D_MODEL + (K0) + xs * 8;           \
      const ushort_t* gb = Bg + (size_t)row * D_MODEL + (K0) + xs * 8;           \
      ushort_t* la = sh + (BUF) * 8192 + (q * 256 + wv * 64) * 8;                \
      ushort_t* lb = sh + (BUF) * 8192 + 4096 + (q * 256 + wv * 64) * 8;         \
      __builtin_amdgcn_global_load_lds((const __attribute__((address_space(1))) void*)ga, \
                                       (__attribute__((address_space(3))) void*)la, 16, 0, 0); \
      __builtin_amdgcn_global_load_lds((const __attribute__((address_space(1))) void*)gb, \
                                       (__attribute__((address_space(3))) void*)lb, 16, 0, 0); \
    }                                                                            \
  } while (0)

#define COMPUTE(BUF)                                                             \
  do {                                                                           \
    const ushort_t* Ab = sh + (BUF) * 8192;                                      \
    const ushort_t* Bb = sh + (BUF) * 8192 + 4096;                               \
    bf16x8 af[4], bfr[4];                                                        \
    _Pragma("unroll")                                                            \
    for (int m = 0; m < 4; ++m) {                                                \
      int row = wr * 64 + m * 16 + frow;                                         \
      af[m] = *(const bf16x8*)(Ab + (row * 4 + (ksel ^ ((row >> 1) & 3))) * 8);  \
    }                                                                            \
    _Pragma("unroll")                                                            \
    for (int n = 0; n < 4; ++n) {                                                \
      int row = wc * 64 + n * 16 + frow;                                         \
      bfr[n] = *(const bf16x8*)(Bb + (row * 4 + (ksel ^ ((row >> 1) & 3))) * 8); \
    }                                                                            \
    _Pragma("unroll")                                                            \
    for (int m = 0; m < 4; ++m)                                                  \
      _Pragma("unroll")                                                          \
      for (int n = 0; n < 4; ++n)                                                \
        acc[m][n] = __builtin_amdgcn_mfma_f32_16x16x32_bf16(af[m], bfr[n], acc[m][n], 0, 0, 0); \
  } while (0)

  STAGE_IN(0, 0);
  STAGE_IN(1, 32);
  asm volatile("s_waitcnt vmcnt(4)" ::: "memory");
  __builtin_amdgcn_s_barrier();

  for (int t = 0; t < 30; ++t) {
    COMPUTE(t & 1);
    __builtin_amdgcn_sched_barrier(0);
    __builtin_amdgcn_s_barrier();
    STAGE_IN(t & 1, (t + 2) * 32);
    asm volatile("s_waitcnt vmcnt(4)" ::: "memory");
    __builtin_amdgcn_s_barrier();
    __builtin_amdgcn_sched_barrier(0);
  }
  COMPUTE(0);
  __builtin_amdgcn_sched_barrier(0);
  __builtin_amdgcn_s_barrier();
  asm volatile("s_waitcnt vmcnt(0)" ::: "memory");
  __builtin_amdgcn_s_barrier();
  COMPUTE(1);
#undef STAGE_IN
#undef COMPUTE

  __syncthreads();

  const int crow0 = (lane >> 4) * 4;
  const int ccol  = lane & 15;
#pragma unroll
  for (int m = 0; m < 4; ++m) {
#pragma unroll
    for (int n = 0; n < 4; ++n) {
      int r0 = wr * 64 + m * 16 + crow0;
      int c  = wc * 64 + n * 16 + ccol;
#pragma unroll
      for (int i = 0; i < 4; ++i)
        sh[(r0 + i) * 136 + c] = f2bf(acc[m][n][i]);
    }
  }
  __syncthreads();
  ushort_t* Cb = Cout + (size_t)b * D_INNER * L_SEQ
                      + (size_t)(bm * 128) * L_SEQ + bn * 128;
#pragma unroll
  for (int q = 0; q < 8; ++q) {
    int idx = q * 256 + tid;
    int r   = idx >> 4;
    int c16 = idx & 15;
    us8 v = *(const us8*)(sh + r * 136 + c16 * 8);
    *(us8*)(Cb + (size_t)r * L_SEQ + c16 * 8) = v;
  }
}

// ---------------------------------------------------------------------------
// K3: x_proj via bf16 MFMA + fused conv4+SiLU. Split-K 4, N-tile 64.
// FIXED from round 10: B-staging is 256 tasks (n4 = tid&15, kp = tid>>4,
// kp 0..15 -> d-pair within the 32-deep K-tile; 2*kp <= 30 < 34 row stride).
// Grid (ln=32, sk=4, b=4) = 512 blocks, 256 thr (4 waves 2x2: M 2x48, N 2x32).
// ---------------------------------------------------------------------------
__global__ __launch_bounds__(256) void k_xproj_fused(
    const ushort_t* __restrict__ XWb,  // [96][2048] bf16
    const ushort_t* __restrict__ Xpre, // [B][D_INNER][L] bf16 (pre-conv)
    const float* __restrict__ CW,      // [D_INNER][4] conv weights
    const float* __restrict__ CB,      // [D_INNER] conv bias
    float* __restrict__ Xout,          // [B][D_INNER][L] fp32 (post conv+silu)
    float* __restrict__ XDBL,          // [B][64][L] fp32 (atomic)
    float* __restrict__ OutB,          // [B][16][L]  (atomic)
    float* __restrict__ OutC) {        // [B][16][L]  (atomic)
  const int ln = blockIdx.x;   // 0..31 (l-tile of 64)
  const int sk = blockIdx.y;   // 0..3  (d-range of 512)
  const int b  = blockIdx.z;
  __shared__ ushort_t As[96 * 40];
  __shared__ ushort_t Bs[64 * 34];
  const int tid  = threadIdx.x;
  const int wv   = tid >> 6;
  const int lane = tid & 63;
  const int wr = wv >> 1, wc = wv & 1;
  const int ksel = lane >> 4;
  const int frow = lane & 15;

  f32x4 acc[3][2];
#pragma unroll
  for (int i = 0; i < 3; ++i)
#pragma unroll
    for (int j = 0; j < 2; ++j) acc[i][j] = (f32x4){0.f, 0.f, 0.f, 0.f};

  for (int k0 = 0; k0 < 512; k0 += 32) {
    const int koff = sk * 512 + k0;
    // ---- stage A tile [96][32] ----
    {
      int row = tid >> 2, s = tid & 3;
      bf16x8 v = *(const bf16x8*)(XWb + (size_t)row * D_INNER + koff + s * 8);
      *(bf16x8*)(As + row * 40 + s * 8) = v;
      if (tid < 128) {
        int row2 = 64 + (tid >> 2);
        bf16x8 v2 = *(const bf16x8*)(XWb + (size_t)row2 * D_INNER + koff + s * 8);
        *(bf16x8*)(As + row2 * 40 + s * 8) = v2;
      }
    }
    // ---- stage B tile [32 d][64 l]: 256 tasks, one per thread ----
    {
      int n4 = tid & 15;         // l-quad (16 quads = 64 l)
      int kp = tid >> 4;         // d-pair 0..15 (32 d = K-tile depth)
      int l0 = ln * 64 + 4 * n4;
      float sv[2][4];
#pragma unroll
      for (int r = 0; r < 2; ++r) {
        int d = koff + 2 * kp + r;
        const ushort_t* row = Xpre + ((size_t)b * D_INNER + d) * L_SEQ;
        ushort4 cur = *(const ushort4*)(row + l0);
        float em3 = 0.f, em2 = 0.f, em1 = 0.f;
        if (l0 >= 4) {
          ushort4 pv = *(const ushort4*)(row + l0 - 4);
          em3 = bf2f(pv.y); em2 = bf2f(pv.z); em1 = bf2f(pv.w);
        }
        float ee[7] = {em3, em2, em1, bf2f(cur.x), bf2f(cur.y), bf2f(cur.z), bf2f(cur.w)};
        float4 w = *(const float4*)(CW + d * 4);
        float bias = CB[d];
#pragma unroll
        for (int i = 0; i < 4; ++i) {
          float v = w.x * ee[i] + w.y * ee[i + 1] + w.z * ee[i + 2] + w.w * ee[i + 3] + bias;
          sv[r][i] = v / (1.f + expf(-v));
        }
        *(float4*)(Xout + ((size_t)b * D_INNER + d) * L_SEQ + l0) =
            make_float4(sv[r][0], sv[r][1], sv[r][2], sv[r][3]);
      }
#pragma unroll
      for (int i = 0; i < 4; ++i) {
        uint_t pk = (uint_t)f2bf(sv[0][i]) | ((uint_t)f2bf(sv[1][i]) << 16);
        *(uint_t*)(Bs + (4 * n4 + i) * 34 + 2 * kp) = pk;
      }
    }
    __syncthreads();

    // ---- fragments ----
    bf16x8 af[3], bfr[2];
#pragma unroll
    for (int mi = 0; mi < 3; ++mi) {
      int row = wr * 48 + mi * 16 + frow;
      af[mi] = *(const bf16x8*)(As + row * 40 + ksel * 8);
    }
#pragma unroll
    for (int ni = 0; ni < 2; ++ni) {
      int n = wc * 32 + ni * 16 + frow;
      const uint_t* p = (const uint_t*)(Bs + n * 34);
      union { uint_t u[4]; bf16x8 v; } fr;
#pragma unroll
      for (int q = 0; q < 4; ++q) fr.u[q] = p[ksel * 4 + q];
      bfr[ni] = fr.v;
    }
#pragma unroll
    for (int mi = 0; mi < 3; ++mi)
#pragma unroll
      for (int ni = 0; ni < 2; ++ni)
        acc[mi][ni] = __builtin_amdgcn_mfma_f32_16x16x32_bf16(af[mi], bfr[ni], acc[mi][ni], 0, 0, 0);
    __syncthreads();
  }

  // ---- epilogue: atomic accumulate (4-way contention) ----
  const int crow0 = (lane >> 4) * 4;
  const int ccol  = lane & 15;
#pragma unroll
  for (int mi = 0; mi < 3; ++mi) {
    int e0 = wr * 48 + mi * 16 + crow0;
    float* base;
    int eoff;
    if (e0 < 64)      { base = XDBL + (size_t)b * 64 * L_SEQ; eoff = e0; }
    else if (e0 < 80) { base = OutB + (size_t)b * D_STATE * L_SEQ; eoff = e0 - 64; }
    else              { base = OutC + (size_t)b * D_STATE * L_SEQ; eoff = e0 - 80; }
#pragma unroll
    for (int ni = 0; ni < 2; ++ni) {
      int l = ln * 64 + wc * 32 + ni * 16 + ccol;
#pragma unroll
      for (int r = 0; r < 4; ++r)
        atomicAdd(base + (size_t)(eoff + r) * L_SEQ + l, acc[mi][ni][r]);
    }
  }
}

// ---------------------------------------------------------------------------
// K4: dt GEMM via bf16 MFMA. DT[b][d][l] = sum_r DW[d][r] * XDBL[b][r][l].
// K=64 single-stage; 128x128 tile; 4 waves (2x2); write-bound epilogue.
// ---------------------------------------------------------------------------
__global__ __launch_bounds__(256) void k_dt_mfma(
    const ushort_t* __restrict__ DWb,  // [D_INNER][64] bf16
    const float* __restrict__ XDBL,    // [B][64][L] fp32
    float* __restrict__ DT) {          // [B][D_INNER][L] fp32
  const int ln = blockIdx.x;   // 0..15 (l tile)
  const int dm = blockIdx.y;   // 0..15 (d tile)
  const int b  = blockIdx.z;
  __shared__ ushort_t As[128 * 72];    // [d][r], pad 72
  __shared__ ushort_t Bs[128 * 68];    // [l][r], pad 68
  const int tid  = threadIdx.x;
  const int wv   = tid >> 6;
  const int lane = tid & 63;
  const int wr = wv >> 1, wc = wv & 1;
  const int ksel = lane >> 4;
  const int frow = lane & 15;

#pragma unroll
  for (int q = 0; q < 4; ++q) {
    int u = tid + 256 * q;
    int row = u >> 3, s = u & 7;
    *(bf16x8*)(As + row * 72 + s * 8) =
        *(const bf16x8*)(DWb + (size_t)(dm * 128 + row) * DT_RANK + s * 8);
  }
#pragma unroll
  for (int q = 0; q < 4; ++q) {
    int u = tid + 256 * q;
    int n4 = u & 31;
    int kp = u >> 5;
    const float* g = XDBL + ((size_t)b * DT_RANK + 2 * kp) * L_SEQ + ln * 128 + 4 * n4;
    float4 x0 = *(const float4*)g;
    float4 x1 = *(const float4*)(g + L_SEQ);
    float e0[4] = {x0.x, x0.y, x0.z, x0.w};
    float e1[4] = {x1.x, x1.y, x1.z, x1.w};
#pragma unroll
    for (int i = 0; i < 4; ++i) {
      uint_t pk = (uint_t)f2bf(e0[i]) | ((uint_t)f2bf(e1[i]) << 16);
      *(uint_t*)(Bs + (4 * n4 + i) * 68 + 2 * kp) = pk;
    }
  }
  __syncthreads();

  f32x4 acc[4][4];
#pragma unroll
  for (int i = 0; i < 4; ++i)
#pragma unroll
    for (int j = 0; j < 4; ++j) acc[i][j] = (f32x4){0.f, 0.f, 0.f, 0.f};

#pragma unroll
  for (int ks = 0; ks < 2; ++ks) {
    bf16x8 af[4], bfr[4];
#pragma unroll
    for (int m = 0; m < 4; ++m) {
      int row = wr * 64 + m * 16 + frow;
      af[m] = *(const bf16x8*)(As + row * 72 + ks * 32 + ksel * 8);
    }
#pragma unroll
    for (int n = 0; n < 4; ++n) {
      int nn = wc * 64 + n * 16 + frow;
      bfr[n] = *(const bf16x8*)(Bs + nn * 68 + ks * 32 + ksel * 8);
    }
#pragma unroll
    for (int m = 0; m < 4; ++m)
#pragma unroll
      for (int n = 0; n < 4; ++n)
        acc[m][n] = __builtin_amdgcn_mfma_f32_16x16x32_bf16(af[m], bfr[n], acc[m][n], 0, 0, 0);
  }

  const int crow0 = (lane >> 4) * 4;
  const int ccol  = lane & 15;
  float* Cb = DT + (size_t)b * D_INNER * L_SEQ;
#pragma unroll
  for (int m = 0; m < 4; ++m) {
    int gr0 = dm * 128 + wr * 64 + m * 16 + crow0;
#pragma unroll
    for (int n = 0; n < 4; ++n) {
      int gc = ln * 128 + wc * 64 + n * 16 + ccol;
#pragma unroll
      for (int i = 0; i < 4; ++i)
        Cb[(size_t)(gr0 + i) * L_SEQ + gc] = acc[m][n][i];
    }
  }
}

extern "C" void kernel_launch(void* const* d_in, const int* in_sizes, int n_in,
                              void* d_out, int out_size, void* d_ws, size_t ws_size,
                              hipStream_t stream) {
  const float* hs   = (const float*)d_in[0];
  const float* ipw  = (const float*)d_in[1];
  const float* cw   = (const float*)d_in[2];
  const float* cb   = (const float*)d_in[3];
  const float* xpw  = (const float*)d_in[4];
  const float* dpw  = (const float*)d_in[5];
  const float* alog = (const float*)d_in[6];

  float* out    = (float*)d_out;
  float* dt_out = out + OFF_DT;
  float* a_out  = out + OFF_A;
  float* b_out  = out + OFF_B;
  float* c_out  = out + OFF_C;
  float* x_out  = out + OFF_X;

  // Scratch plan:
  //  - bf16 HS (16.8 MB) + bf16 W-half (4.2 MB) in x region of d_out (dead
  //    after k_inproj; k_xproj_fused overwrites x region afterwards).
  //  - xpre (pre-conv x, bf16, 33.5 MB) in dt region (dead after xproj;
  //    k_dt_mfma overwrites).
  //  - d_ws: xdbl fp32 (2 MB) | XWb bf16 (384 KB) | DWb bf16 (256 KB).
  unsigned short* bfHS = (unsigned short*)x_out;
  unsigned short* bfW  = bfHS + (size_t)B_SZ * L_SEQ * D_MODEL;
  unsigned short* xpre = (unsigned short*)dt_out;
  float* xdbl = (float*)d_ws;
  unsigned short* xwb = (unsigned short*)((char*)d_ws + 2097152);
  unsigned short* dwb = (unsigned short*)((char*)d_ws + 2097152 + 393216);

  // One fused prep launch: 4 casts + zero xdbl + zero B|C + A = -exp(A_log).
  k_prep<<<dim3((N4_TOT + 255) / 256), 256, 0, stream>>>(
      (const float4*)hs, (const float4*)ipw, (const float4*)xpw,
      (const float4*)dpw, (const float4*)alog,
      (ushort4*)bfHS, (ushort4*)bfW, (ushort4*)xwb, (ushort4*)dwb,
      (float4*)xdbl, (float4*)b_out, (float4*)a_out);

  k_inproj_mfma<<<dim3(16, 16, 4), 256, 0, stream>>>(bfW, bfHS, xpre);
  k_xproj_fused<<<dim3(32, 4, 4), 256, 0, stream>>>(xwb, xpre, cw, cb,
                                                    x_out, xdbl, b_out, c_out);
  k_dt_mfma<<<dim3(16, 16, 4), 256, 0, stream>>>(dwb, xdbl, dt_out);
}

// Round 12
// 119.998 us; speedup vs baseline: 1.2976x; 1.0440x over previous
//
#include <hip/hip_runtime.h>
#include <hip/hip_bf16.h>
#include <math.h>

#define D_MODEL 1024
#define D_STATE 16
#define D_CONV  4
#define D_INNER 2048
#define DT_RANK 64
#define B_SZ    4
#define L_SEQ   2048

// d_out layout (floats): dt | A | B | C | x
#define OFF_DT 0
#define OFF_A  (B_SZ * D_INNER * L_SEQ)
#define OFF_B  (OFF_A + D_INNER * D_STATE)
#define OFF_C  (OFF_B + B_SZ * D_STATE * L_SEQ)
#define OFF_X  (OFF_C + B_SZ * D_STATE * L_SEQ)

typedef __attribute__((ext_vector_type(8))) short bf16x8;
typedef __attribute__((ext_vector_type(8))) unsigned short us8;
typedef __attribute__((ext_vector_type(4))) float f32x4;
typedef unsigned short ushort_t;
typedef unsigned int uint_t;

static __device__ __forceinline__ ushort_t f2bf(float f) {
  __hip_bfloat16 h = __float2bfloat16(f);
  return *(ushort_t*)&h;
}
static __device__ __forceinline__ float bf2f(ushort_t u) {
  union { uint_t u; float f; } c;
  c.u = ((uint_t)u) << 16;
  return c.f;
}

// ---------------------------------------------------------------------------
// K0: fused prep — bf16 casts (hs, in_proj x-half, x_proj_w, dt_proj_w),
// zero split-K targets (xdbl, B|C), and A = -exp(A_log). One launch.
// ---------------------------------------------------------------------------
#define N4_HS   (B_SZ * L_SEQ * D_MODEL / 4)                 // 2097152
#define N4_W    (D_INNER * D_MODEL / 4)                      // 524288
#define N4_XW   ((DT_RANK + 2 * D_STATE) * D_INNER / 4)      // 49152
#define N4_DW   (D_INNER * DT_RANK / 4)                      // 32768
#define N4_Z0   (B_SZ * DT_RANK * L_SEQ / 4)                 // 131072 (xdbl)
#define N4_Z1   (2 * B_SZ * D_STATE * L_SEQ / 4)             // 65536  (B|C)
#define N4_A    (D_INNER * D_STATE / 4)                      // 8192   (A)
#define N4_TOT  (N4_HS + N4_W + N4_XW + N4_DW + N4_Z0 + N4_Z1 + N4_A)

__global__ __launch_bounds__(256) void k_prep(
    const float4* __restrict__ hs, const float4* __restrict__ ipw,
    const float4* __restrict__ xpw, const float4* __restrict__ dpw,
    const float4* __restrict__ alog,
    ushort4* __restrict__ bfHS, ushort4* __restrict__ bfW,
    ushort4* __restrict__ xwb, ushort4* __restrict__ dwb,
    float4* __restrict__ z0, float4* __restrict__ z1,
    float4* __restrict__ aout) {
  int i = blockIdx.x * 256 + threadIdx.x;
  if (i < N4_HS) {
    float4 v = hs[i];
    ushort4 o; o.x = f2bf(v.x); o.y = f2bf(v.y); o.z = f2bf(v.z); o.w = f2bf(v.w);
    bfHS[i] = o;
    return;
  }
  i -= N4_HS;
  if (i < N4_W) {
    float4 v = ipw[i];
    ushort4 o; o.x = f2bf(v.x); o.y = f2bf(v.y); o.z = f2bf(v.z); o.w = f2bf(v.w);
    bfW[i] = o;
    return;
  }
  i -= N4_W;
  if (i < N4_XW) {
    float4 v = xpw[i];
    ushort4 o; o.x = f2bf(v.x); o.y = f2bf(v.y); o.z = f2bf(v.z); o.w = f2bf(v.w);
    xwb[i] = o;
    return;
  }
  i -= N4_XW;
  if (i < N4_DW) {
    float4 v = dpw[i];
    ushort4 o; o.x = f2bf(v.x); o.y = f2bf(v.y); o.z = f2bf(v.z); o.w = f2bf(v.w);
    dwb[i] = o;
    return;
  }
  i -= N4_DW;
  if (i < N4_Z0) { z0[i] = (float4){0.f, 0.f, 0.f, 0.f}; return; }
  i -= N4_Z0;
  if (i < N4_Z1) { z1[i] = (float4){0.f, 0.f, 0.f, 0.f}; return; }
  i -= N4_Z1;
  if (i < N4_A) {
    float4 v = alog[i];
    float4 o;
    o.x = -expf(v.x); o.y = -expf(v.y); o.z = -expf(v.z); o.w = -expf(v.w);
    aout[i] = o;
  }
}

// ---------------------------------------------------------------------------
// K1: in_proj (x half) via bf16 MFMA — 256x256 tile, BK=64, 512 thr / 8 waves
// (2M x 4N; per-wave 128x64 = 8x4 fragments). Counted-vmcnt 2-deep pipeline
// (round-9 ledger, scaled: 8 gl_lds per K-tile stage, vmcnt(8) => prev tile
// landed) + T5 setprio around MFMA clusters + LDS-staged 2-panel epilogue.
// LDS 128 KB: 2 bufs x {A,B} x {half 0,1} x {ksub 0,1} x [128 rows][4 slots
// of 16B], slot-XOR s^((r>>1)&3) (proven involution from round 2).
// ---------------------------------------------------------------------------
__global__ __launch_bounds__(512, 2) void k_inproj_mfma(
    const ushort_t* __restrict__ Wb,   // [D_INNER][D_MODEL] bf16
    const ushort_t* __restrict__ HSb,  // [B][L][D_MODEL] bf16
    ushort_t* __restrict__ Cout) {     // [B][D_INNER][L] bf16
  // grid (8,8,4) = 256 blocks; XCD-aware bijective swizzle (256 % 8 == 0).
  const int flat = blockIdx.x + 8 * blockIdx.y + 64 * blockIdx.z;
  const int swz  = (flat & 7) * 32 + (flat >> 3);
  const int bn = swz & 7;
  const int bm = (swz >> 3) & 7;
  const int b  = swz >> 6;

  __shared__ ushort_t sh[65536];  // 128 KB
  const int tid  = threadIdx.x;
  const int w    = tid >> 6;
  const int lane = tid & 63;
  const int wm = w >> 2, wn = w & 3;
  const int ksel = lane >> 4;
  const int frow = lane & 15;
  const int sr = tid >> 2;        // staging row 0..127
  const int ss = tid & 3;         // staging slot 0..3

  const ushort_t* Ag = Wb + (size_t)(bm * 256) * D_MODEL;
  const ushort_t* Bg = HSb + (size_t)b * L_SEQ * D_MODEL
                           + (size_t)(bn * 256) * D_MODEL;

  f32x4 acc[8][4];
#pragma unroll
  for (int m = 0; m < 8; ++m)
#pragma unroll
    for (int n = 0; n < 4; ++n) acc[m][n] = (f32x4){0.f, 0.f, 0.f, 0.f};

  const int sxs = ss ^ ((sr >> 1) & 3);  // pre-swizzled global slot

  // 8 gl_lds per thread per K-tile: {A,B} x {half} x {ksub}.
#define STAGE(BUF, T)                                                            \
  do {                                                                           \
    _Pragma("unroll")                                                            \
    for (int mh = 0; mh < 4; ++mh) {                                             \
      const ushort_t* gbase = (mh < 2) ? Ag : Bg;                                \
      const ushort_t* grow = gbase + (size_t)((mh & 1) * 128 + sr) * D_MODEL     \
                                   + (T) * 64 + sxs * 8;                         \
      _Pragma("unroll")                                                          \
      for (int q = 0; q < 2; ++q) {                                              \
        ushort_t* dst = sh + (BUF) * 32768 + (mh >> 1) * 16384                   \
                           + (mh & 1) * 8192 + q * 4096 + tid * 8;               \
        __builtin_amdgcn_global_load_lds(                                        \
            (const __attribute__((address_space(1))) void*)(grow + q * 32),      \
            (__attribute__((address_space(3))) void*)dst, 16, 0, 0);             \
      }                                                                          \
    }                                                                            \
  } while (0)

#define COMPUTE(BUF)                                                             \
  do {                                                                           \
    _Pragma("unroll")                                                            \
    for (int ks = 0; ks < 2; ++ks) {                                             \
      bf16x8 af[8], bfr[4];                                                      \
      _Pragma("unroll")                                                          \
      for (int m = 0; m < 8; ++m) {                                              \
        int r = m * 16 + frow;                                                   \
        af[m] = *(const bf16x8*)(sh + (BUF) * 32768 + wm * 8192 + ks * 4096      \
                                 + (r * 4 + (ksel ^ ((r >> 1) & 3))) * 8);       \
      }                                                                          \
      _Pragma("unroll")                                                          \
      for (int n = 0; n < 4; ++n) {                                              \
        int ll = wn * 64 + n * 16 + frow;                                        \
        int h = ll >> 7, r = ll & 127;                                           \
        bfr[n] = *(const bf16x8*)(sh + (BUF) * 32768 + 16384 + h * 8192          \
                                  + ks * 4096                                    \
                                  + (r * 4 + (ksel ^ ((r >> 1) & 3))) * 8);      \
      }                                                                          \
      __builtin_amdgcn_s_setprio(1);                                             \
      _Pragma("unroll")                                                          \
      for (int m = 0; m < 8; ++m)                                                \
        _Pragma("unroll")                                                        \
        for (int n = 0; n < 4; ++n)                                              \
          acc[m][n] = __builtin_amdgcn_mfma_f32_16x16x32_bf16(af[m], bfr[n],     \
                                                              acc[m][n], 0, 0, 0); \
      __builtin_amdgcn_s_setprio(0);                                             \
    }                                                                            \
  } while (0)

  // ---- prologue: stage K-tiles 0,1 ----
  STAGE(0, 0);
  STAGE(1, 1);
  asm volatile("s_waitcnt vmcnt(8)" ::: "memory");  // tile 0 landed
  __builtin_amdgcn_s_barrier();

  // ---- main loop: 16 K-tiles total, 14 pipelined iterations ----
  for (int t = 0; t < 14; ++t) {
    COMPUTE(t & 1);
    __builtin_amdgcn_sched_barrier(0);
    __builtin_amdgcn_s_barrier();                    // buf[t&1] reads done
    STAGE(t & 1, t + 2);
    asm volatile("s_waitcnt vmcnt(8)" ::: "memory"); // tile t+1 landed
    __builtin_amdgcn_s_barrier();
    __builtin_amdgcn_sched_barrier(0);
  }
  COMPUTE(0);                                        // tile 14
  __builtin_amdgcn_sched_barrier(0);
  __builtin_amdgcn_s_barrier();
  asm volatile("s_waitcnt vmcnt(0)" ::: "memory");   // tile 15 landed
  __builtin_amdgcn_s_barrier();
  COMPUTE(1);                                        // tile 15
#undef STAGE
#undef COMPUTE

  __syncthreads();  // all LDS buffer reads done; reuse sh for epilogue

  // ---- epilogue: 2 panels of 128 rows via LDS [128][272], us8 stores ----
  const int crow0 = (lane >> 4) * 4;
  const int ccol  = lane & 15;
  ushort_t* Cb = Cout + (size_t)b * D_INNER * L_SEQ;
#pragma unroll
  for (int p = 0; p < 2; ++p) {
    if (wm == p) {
#pragma unroll
      for (int m = 0; m < 8; ++m)
#pragma unroll
        for (int n = 0; n < 4; ++n) {
          int r0 = m * 16 + crow0;
          int c  = wn * 64 + n * 16 + ccol;
#pragma unroll
          for (int i = 0; i < 4; ++i)
            sh[(r0 + i) * 272 + c] = f2bf(acc[m][n][i]);
        }
    }
    __syncthreads();
#pragma unroll
    for (int q = 0; q < 8; ++q) {
      int idx = q * 512 + tid;     // 4096 16B-chunks (128 rows x 32)
      int r   = idx >> 5;
      int c8  = idx & 31;
      us8 v = *(const us8*)(sh + r * 272 + c8 * 8);
      *(us8*)(Cb + (size_t)(bm * 256 + p * 128 + r) * L_SEQ + bn * 256 + c8 * 8) = v;
    }
    __syncthreads();
  }
}

// ---------------------------------------------------------------------------
// K3: x_proj via bf16 MFMA + fused conv4+SiLU. Split-K 4, N-tile 64.
// (unchanged from round 11)
// ---------------------------------------------------------------------------
__global__ __launch_bounds__(256) void k_xproj_fused(
    const ushort_t* __restrict__ XWb,  // [96][2048] bf16
    const ushort_t* __restrict__ Xpre, // [B][D_INNER][L] bf16 (pre-conv)
    const float* __restrict__ CW,      // [D_INNER][4] conv weights
    const float* __restrict__ CB,      // [D_INNER] conv bias
    float* __restrict__ Xout,          // [B][D_INNER][L] fp32 (post conv+silu)
    float* __restrict__ XDBL,          // [B][64][L] fp32 (atomic)
    float* __restrict__ OutB,          // [B][16][L]  (atomic)
    float* __restrict__ OutC) {        // [B][16][L]  (atomic)
  const int ln = blockIdx.x;   // 0..31 (l-tile of 64)
  const int sk = blockIdx.y;   // 0..3  (d-range of 512)
  const int b  = blockIdx.z;
  __shared__ ushort_t As[96 * 40];
  __shared__ ushort_t Bs[64 * 34];
  const int tid  = threadIdx.x;
  const int wv   = tid >> 6;
  const int lane = tid & 63;
  const int wr = wv >> 1, wc = wv & 1;
  const int ksel = lane >> 4;
  const int frow = lane & 15;

  f32x4 acc[3][2];
#pragma unroll
  for (int i = 0; i < 3; ++i)
#pragma unroll
    for (int j = 0; j < 2; ++j) acc[i][j] = (f32x4){0.f, 0.f, 0.f, 0.f};

  for (int k0 = 0; k0 < 512; k0 += 32) {
    const int koff = sk * 512 + k0;
    // ---- stage A tile [96][32] ----
    {
      int row = tid >> 2, s = tid & 3;
      bf16x8 v = *(const bf16x8*)(XWb + (size_t)row * D_INNER + koff + s * 8);
      *(bf16x8*)(As + row * 40 + s * 8) = v;
      if (tid < 128) {
        int row2 = 64 + (tid >> 2);
        bf16x8 v2 = *(const bf16x8*)(XWb + (size_t)row2 * D_INNER + koff + s * 8);
        *(bf16x8*)(As + row2 * 40 + s * 8) = v2;
      }
    }
    // ---- stage B tile [32 d][64 l]: 256 tasks, one per thread ----
    {
      int n4 = tid & 15;
      int kp = tid >> 4;
      int l0 = ln * 64 + 4 * n4;
      float sv[2][4];
#pragma unroll
      for (int r = 0; r < 2; ++r) {
        int d = koff + 2 * kp + r;
        const ushort_t* row = Xpre + ((size_t)b * D_INNER + d) * L_SEQ;
        ushort4 cur = *(const ushort4*)(row + l0);
        float em3 = 0.f, em2 = 0.f, em1 = 0.f;
        if (l0 >= 4) {
          ushort4 pv = *(const ushort4*)(row + l0 - 4);
          em3 = bf2f(pv.y); em2 = bf2f(pv.z); em1 = bf2f(pv.w);
        }
        float ee[7] = {em3, em2, em1, bf2f(cur.x), bf2f(cur.y), bf2f(cur.z), bf2f(cur.w)};
        float4 w = *(const float4*)(CW + d * 4);
        float bias = CB[d];
#pragma unroll
        for (int i = 0; i < 4; ++i) {
          float v = w.x * ee[i] + w.y * ee[i + 1] + w.z * ee[i + 2] + w.w * ee[i + 3] + bias;
          sv[r][i] = v / (1.f + expf(-v));
        }
        *(float4*)(Xout + ((size_t)b * D_INNER + d) * L_SEQ + l0) =
            make_float4(sv[r][0], sv[r][1], sv[r][2], sv[r][3]);
      }
#pragma unroll
      for (int i = 0; i < 4; ++i) {
        uint_t pk = (uint_t)f2bf(sv[0][i]) | ((uint_t)f2bf(sv[1][i]) << 16);
        *(uint_t*)(Bs + (4 * n4 + i) * 34 + 2 * kp) = pk;
      }
    }
    __syncthreads();

    // ---- fragments ----
    bf16x8 af[3], bfr[2];
#pragma unroll
    for (int mi = 0; mi < 3; ++mi) {
      int row = wr * 48 + mi * 16 + frow;
      af[mi] = *(const bf16x8*)(As + row * 40 + ksel * 8);
    }
#pragma unroll
    for (int ni = 0; ni < 2; ++ni) {
      int n = wc * 32 + ni * 16 + frow;
      const uint_t* p = (const uint_t*)(Bs + n * 34);
      union { uint_t u[4]; bf16x8 v; } fr;
#pragma unroll
      for (int q = 0; q < 4; ++q) fr.u[q] = p[ksel * 4 + q];
      bfr[ni] = fr.v;
    }
#pragma unroll
    for (int mi = 0; mi < 3; ++mi)
#pragma unroll
      for (int ni = 0; ni < 2; ++ni)
        acc[mi][ni] = __builtin_amdgcn_mfma_f32_16x16x32_bf16(af[mi], bfr[ni], acc[mi][ni], 0, 0, 0);
    __syncthreads();
  }

  // ---- epilogue: atomic accumulate (4-way contention) ----
  const int crow0 = (lane >> 4) * 4;
  const int ccol  = lane & 15;
#pragma unroll
  for (int mi = 0; mi < 3; ++mi) {
    int e0 = wr * 48 + mi * 16 + crow0;
    float* base;
    int eoff;
    if (e0 < 64)      { base = XDBL + (size_t)b * 64 * L_SEQ; eoff = e0; }
    else if (e0 < 80) { base = OutB + (size_t)b * D_STATE * L_SEQ; eoff = e0 - 64; }
    else              { base = OutC + (size_t)b * D_STATE * L_SEQ; eoff = e0 - 80; }
#pragma unroll
    for (int ni = 0; ni < 2; ++ni) {
      int l = ln * 64 + wc * 32 + ni * 16 + ccol;
#pragma unroll
      for (int r = 0; r < 4; ++r)
        atomicAdd(base + (size_t)(eoff + r) * L_SEQ + l, acc[mi][ni][r]);
    }
  }
}

// ---------------------------------------------------------------------------
// K4: dt GEMM via bf16 MFMA. (unchanged from round 11)
// ---------------------------------------------------------------------------
__global__ __launch_bounds__(256) void k_dt_mfma(
    const ushort_t* __restrict__ DWb,  // [D_INNER][64] bf16
    const float* __restrict__ XDBL,    // [B][64][L] fp32
    float* __restrict__ DT) {          // [B][D_INNER][L] fp32
  const int ln = blockIdx.x;
  const int dm = blockIdx.y;
  const int b  = blockIdx.z;
  __shared__ ushort_t As[128 * 72];
  __shared__ ushort_t Bs[128 * 68];
  const int tid  = threadIdx.x;
  const int wv   = tid >> 6;
  const int lane = tid & 63;
  const int wr = wv >> 1, wc = wv & 1;
  const int ksel = lane >> 4;
  const int frow = lane & 15;

#pragma unroll
  for (int q = 0; q < 4; ++q) {
    int u = tid + 256 * q;
    int row = u >> 3, s = u & 7;
    *(bf16x8*)(As + row * 72 + s * 8) =
        *(const bf16x8*)(DWb + (size_t)(dm * 128 + row) * DT_RANK + s * 8);
  }
#pragma unroll
  for (int q = 0; q < 4; ++q) {
    int u = tid + 256 * q;
    int n4 = u & 31;
    int kp = u >> 5;
    const float* g = XDBL + ((size_t)b * DT_RANK + 2 * kp) * L_SEQ + ln * 128 + 4 * n4;
    float4 x0 = *(const float4*)g;
    float4 x1 = *(const float4*)(g + L_SEQ);
    float e0[4] = {x0.x, x0.y, x0.z, x0.w};
    float e1[4] = {x1.x, x1.y, x1.z, x1.w};
#pragma unroll
    for (int i = 0; i < 4; ++i) {
      uint_t pk = (uint_t)f2bf(e0[i]) | ((uint_t)f2bf(e1[i]) << 16);
      *(uint_t*)(Bs + (4 * n4 + i) * 68 + 2 * kp) = pk;
    }
  }
  __syncthreads();

  f32x4 acc[4][4];
#pragma unroll
  for (int i = 0; i < 4; ++i)
#pragma unroll
    for (int j = 0; j < 4; ++j) acc[i][j] = (f32x4){0.f, 0.f, 0.f, 0.f};

#pragma unroll
  for (int ks = 0; ks < 2; ++ks) {
    bf16x8 af[4], bfr[4];
#pragma unroll
    for (int m = 0; m < 4; ++m) {
      int row = wr * 64 + m * 16 + frow;
      af[m] = *(const bf16x8*)(As + row * 72 + ks * 32 + ksel * 8);
    }
#pragma unroll
    for (int n = 0; n < 4; ++n) {
      int nn = wc * 64 + n * 16 + frow;
      bfr[n] = *(const bf16x8*)(Bs + nn * 68 + ks * 32 + ksel * 8);
    }
#pragma unroll
    for (int m = 0; m < 4; ++m)
#pragma unroll
      for (int n = 0; n < 4; ++n)
        acc[m][n] = __builtin_amdgcn_mfma_f32_16x16x32_bf16(af[m], bfr[n], acc[m][n], 0, 0, 0);
  }

  const int crow0 = (lane >> 4) * 4;
  const int ccol  = lane & 15;
  float* Cb = DT + (size_t)b * D_INNER * L_SEQ;
#pragma unroll
  for (int m = 0; m < 4; ++m) {
    int gr0 = dm * 128 + wr * 64 + m * 16 + crow0;
#pragma unroll
    for (int n = 0; n < 4; ++n) {
      int gc = ln * 128 + wc * 64 + n * 16 + ccol;
#pragma unroll
      for (int i = 0; i < 4; ++i)
        Cb[(size_t)(gr0 + i) * L_SEQ + gc] = acc[m][n][i];
    }
  }
}

extern "C" void kernel_launch(void* const* d_in, const int* in_sizes, int n_in,
                              void* d_out, int out_size, void* d_ws, size_t ws_size,
                              hipStream_t stream) {
  const float* hs   = (const float*)d_in[0];
  const float* ipw  = (const float*)d_in[1];
  const float* cw   = (const float*)d_in[2];
  const float* cb   = (const float*)d_in[3];
  const float* xpw  = (const float*)d_in[4];
  const float* dpw  = (const float*)d_in[5];
  const float* alog = (const float*)d_in[6];

  float* out    = (float*)d_out;
  float* dt_out = out + OFF_DT;
  float* a_out  = out + OFF_A;
  float* b_out  = out + OFF_B;
  float* c_out  = out + OFF_C;
  float* x_out  = out + OFF_X;

  // Scratch plan:
  //  - bf16 HS (16.8 MB) + bf16 W-half (4.2 MB) in x region of d_out (dead
  //    after k_inproj; k_xproj_fused overwrites x region afterwards).
  //  - xpre (pre-conv x, bf16, 33.5 MB) in dt region (dead after xproj;
  //    k_dt_mfma overwrites).
  //  - d_ws: xdbl fp32 (2 MB) | XWb bf16 (384 KB) | DWb bf16 (256 KB).
  unsigned short* bfHS = (unsigned short*)x_out;
  unsigned short* bfW  = bfHS + (size_t)B_SZ * L_SEQ * D_MODEL;
  unsigned short* xpre = (unsigned short*)dt_out;
  float* xdbl = (float*)d_ws;
  unsigned short* xwb = (unsigned short*)((char*)d_ws + 2097152);
  unsigned short* dwb = (unsigned short*)((char*)d_ws + 2097152 + 393216);

  // One fused prep launch: 4 casts + zero xdbl + zero B|C + A = -exp(A_log).
  k_prep<<<dim3((N4_TOT + 255) / 256), 256, 0, stream>>>(
      (const float4*)hs, (const float4*)ipw, (const float4*)xpw,
      (const float4*)dpw, (const float4*)alog,
      (ushort4*)bfHS, (ushort4*)bfW, (ushort4*)xwb, (ushort4*)dwb,
      (float4*)xdbl, (float4*)b_out, (float4*)a_out);

  k_inproj_mfma<<<dim3(8, 8, 4), 512, 0, stream>>>(bfW, bfHS, xpre);
  k_xproj_fused<<<dim3(32, 4, 4), 256, 0, stream>>>(xwb, xpre, cw, cb,
                                                    x_out, xdbl, b_out, c_out);
  k_dt_mfma<<<dim3(16, 16, 4), 256, 0, stream>>>(dwb, xdbl, dt_out);
}